// Round 4
// baseline (585.732 us; speedup 1.0000x reference)
//
#include <hip/hip_runtime.h>
#include <math.h>

#define NN 50000
#define NE 800000

// ---------------- degree count ----------------
__global__ void k_deg(const int* __restrict__ dst, int e_cnt, int* __restrict__ cnt) {
  int e = blockIdx.x * 256 + threadIdx.x;
  if (e < e_cnt) atomicAdd(&cnt[dst[e]], 1);
}

// ---------------- two-level exclusive scan ----------------
__global__ __launch_bounds__(256) void k_blockred(const int* __restrict__ cnt, int n,
                                                  int* __restrict__ bsum) {
  __shared__ int sd[256];
  int t = threadIdx.x;
  int i = blockIdx.x * 256 + t;
  sd[t] = (i < n) ? cnt[i] : 0;
  __syncthreads();
  for (int o = 128; o > 0; o >>= 1) {
    if (t < o) sd[t] += sd[t + o];
    __syncthreads();
  }
  if (t == 0) bsum[blockIdx.x] = sd[0];
}

__global__ __launch_bounds__(256) void k_scanb(int* __restrict__ bsum, int nb,
                                               int* __restrict__ total) {
  __shared__ int sd[256];
  int t = threadIdx.x;
  int v = (t < nb) ? bsum[t] : 0;
  sd[t] = v;
  __syncthreads();
  for (int o = 1; o < 256; o <<= 1) {
    int u = (t >= o) ? sd[t - o] : 0;
    __syncthreads();
    sd[t] += u;
    __syncthreads();
  }
  if (t < nb) bsum[t] = sd[t] - v;   // exclusive
  if (t == 255) *total = sd[255];
}

__global__ __launch_bounds__(256) void k_scanfinal(const int* __restrict__ cnt, int n,
                                                   const int* __restrict__ bsum,
                                                   int* __restrict__ offs,
                                                   int* __restrict__ cursor,
                                                   float* __restrict__ invd) {
  __shared__ int sd[256];
  int t = threadIdx.x;
  int i = blockIdx.x * 256 + t;
  int v = (i < n) ? cnt[i] : 0;
  sd[t] = v;
  __syncthreads();
  for (int o = 1; o < 256; o <<= 1) {
    int u = (t >= o) ? sd[t - o] : 0;
    __syncthreads();
    sd[t] += u;
    __syncthreads();
  }
  if (i < n) {
    int off = bsum[blockIdx.x] + sd[t] - v;
    offs[i]   = off;
    cursor[i] = off;
    invd[i]   = 1.0f / fmaxf((float)v, 1.0f);
  }
}

// ---------------- scatter edges into CSR ----------------
__global__ void k_scatter(const int* __restrict__ src, const int* __restrict__ dst, int e_cnt,
                          int* __restrict__ cursor, int* __restrict__ csr) {
  int e = blockIdx.x * 256 + threadIdx.x;
  if (e < e_cnt) {
    int d = dst[e];
    int p = atomicAdd(&cursor[d], 1);
    csr[p] = src[e];
  }
}

// ---------------- per-node mean aggregation ----------------
// One wave per node. lane = nsub*16 + cg; 16 neighbor rows in flight per iter
// (4-deep unroll x 4 parallel sub-slots). Avg degree 16 -> typically 1 iter.
__global__ __launch_bounds__(256) void k_aggregate(const float* __restrict__ feat,
                                                   const int* __restrict__ offs,
                                                   const int* __restrict__ csr,
                                                   const float* __restrict__ invd,
                                                   float* __restrict__ mean, int n) {
  int node = blockIdx.x * 4 + (threadIdx.x >> 6);
  int lane = threadIdx.x & 63;
  int nsub = lane >> 4;        // 0..3: neighbor sub-slot
  int cg   = lane & 15;        // 0..15: float4 channel group
  if (node >= n) return;
  int s = offs[node], e = offs[node + 1];

  float ax = 0.f, ay = 0.f, az = 0.f, aw = 0.f;
  if (e > s) {
    int emax = e - 1;
    for (int p0 = s; p0 < e; p0 += 16) {
      int pa = p0 + nsub;
      int pb = p0 + 4 + nsub;
      int pc = p0 + 8 + nsub;
      int pd = p0 + 12 + nsub;
      int ja = csr[pa < emax ? pa : emax];
      int jb = csr[pb < emax ? pb : emax];
      int jc = csr[pc < emax ? pc : emax];
      int jd = csr[pd < emax ? pd : emax];
      float4 va = *(const float4*)(feat + (size_t)ja * 64 + cg * 4);
      float4 vb = *(const float4*)(feat + (size_t)jb * 64 + cg * 4);
      float4 vc = *(const float4*)(feat + (size_t)jc * 64 + cg * 4);
      float4 vd = *(const float4*)(feat + (size_t)jd * 64 + cg * 4);
      if (pa < e) { ax += va.x; ay += va.y; az += va.z; aw += va.w; }
      if (pb < e) { ax += vb.x; ay += vb.y; az += vb.z; aw += vb.w; }
      if (pc < e) { ax += vc.x; ay += vc.y; az += vc.z; aw += vc.w; }
      if (pd < e) { ax += vd.x; ay += vd.y; az += vd.z; aw += vd.w; }
    }
  }
  // reduce across the 4 neighbor sub-slots (lanes differing in bits 4,5)
  ax += __shfl_xor(ax, 16, 64); ax += __shfl_xor(ax, 32, 64);
  ay += __shfl_xor(ay, 16, 64); ay += __shfl_xor(ay, 32, 64);
  az += __shfl_xor(az, 16, 64); az += __shfl_xor(az, 32, 64);
  aw += __shfl_xor(aw, 16, 64); aw += __shfl_xor(aw, 32, 64);

  if (nsub == 0) {
    float d = invd[node];
    float4 o = make_float4(ax * d, ay * d, az * d, aw * d);
    *(float4*)(mean + (size_t)node * 64 + cg * 4) = o;
  }
}

// ---------------- fused multi-source linear ----------------
// out = act( sum_s g_s * A_s @ W_s + bias ); optional fused column-sum into colsum[64].
// 512 threads (8 waves), 64-node tile, thread = 2 nodes x 4 ch.
// Double-buffered LDS staging: prefetch source s+1 into regs during compute of s,
// one barrier per source.
struct LinArgs {
  const float* a[6];
  const float* w[6];
  int gidx[6];        // index into skip (flattened 3x3), or -1 => gate 1.0
  int stride[6];
  int nsrc;
  const float* bias;  // [64]
  const float* skip;  // [9]
  float* out;         // [n,64]
  float* colsum;      // [64] atomic column-sum target, or nullptr
  int n;
  int relu;
};

__global__ __launch_bounds__(512) void k_linear(LinArgs A) {
  __shared__ float sAT[2][64][68];   // [buf][k][node], +4 pad
  const int t   = threadIdx.x;       // 0..511
  const int tx  = t & 15;            // ch group
  const int ty  = t >> 4;            // 0..31 node pair
  const int ch0 = tx * 4;
  const int nn0 = ty * 2;
  const int n0  = blockIdx.x * 64;

  float acc[2][4];
#pragma unroll
  for (int m = 0; m < 2; ++m)
#pragma unroll
    for (int c = 0; c < 4; ++c) acc[m][c] = 0.0f;

  // staging map: two float4 per thread: f = t + 512*i -> row = f>>4 (0..63), cg = f&15
  float4 pf[2];
  auto load_src = [&](int s) {
    const float* a  = A.a[s];
    const int    st = A.stride[s];
#pragma unroll
    for (int i = 0; i < 2; ++i) {
      int f = t + 512 * i;
      int row = f >> 4, cg = f & 15;
      int gr = n0 + row;
      float4 vv = make_float4(0.f, 0.f, 0.f, 0.f);
      if (gr < A.n) vv = *(const float4*)(a + (size_t)gr * st + cg * 4);
      pf[i] = vv;
    }
  };
  auto write_src = [&](int s, int b) {
    float gs = 1.0f;
    if (A.gidx[s] >= 0) {
      float sv = A.skip[A.gidx[s]];
      gs = 1.0f / (1.0f + expf(-sv));
    }
#pragma unroll
    for (int i = 0; i < 2; ++i) {
      int f = t + 512 * i;
      int row = f >> 4, cg = f & 15;
      sAT[b][cg * 4 + 0][row] = pf[i].x * gs;
      sAT[b][cg * 4 + 1][row] = pf[i].y * gs;
      sAT[b][cg * 4 + 2][row] = pf[i].z * gs;
      sAT[b][cg * 4 + 3][row] = pf[i].w * gs;
    }
  };

  load_src(0);
  write_src(0, 0);
  __syncthreads();

  for (int s = 0; s < A.nsrc; ++s) {
    if (s + 1 < A.nsrc) load_src(s + 1);      // prefetch: latency hidden by compute
    const float* w   = A.w[s];
    const float* buf = &sAT[s & 1][0][0];
#pragma unroll 4
    for (int k = 0; k < 64; ++k) {
      float4 wv = *(const float4*)(w + k * 64 + ch0);
      float2 av = *(const float2*)(buf + k * 68 + nn0);
      acc[0][0] += av.x * wv.x; acc[0][1] += av.x * wv.y;
      acc[0][2] += av.x * wv.z; acc[0][3] += av.x * wv.w;
      acc[1][0] += av.y * wv.x; acc[1][1] += av.y * wv.y;
      acc[1][2] += av.y * wv.z; acc[1][3] += av.y * wv.w;
    }
    if (s + 1 < A.nsrc) write_src(s + 1, (s + 1) & 1);
    __syncthreads();
  }

  float4 bv = *(const float4*)(A.bias + ch0);
  float4 o0, o1;
  o0.x = acc[0][0] + bv.x; o0.y = acc[0][1] + bv.y;
  o0.z = acc[0][2] + bv.z; o0.w = acc[0][3] + bv.w;
  o1.x = acc[1][0] + bv.x; o1.y = acc[1][1] + bv.y;
  o1.z = acc[1][2] + bv.z; o1.w = acc[1][3] + bv.w;
  if (A.relu) {
    o0.x = fmaxf(o0.x, 0.f); o0.y = fmaxf(o0.y, 0.f);
    o0.z = fmaxf(o0.z, 0.f); o0.w = fmaxf(o0.w, 0.f);
    o1.x = fmaxf(o1.x, 0.f); o1.y = fmaxf(o1.y, 0.f);
    o1.z = fmaxf(o1.z, 0.f); o1.w = fmaxf(o1.w, 0.f);
  }
  int m0 = n0 + nn0, m1 = m0 + 1;
  bool v0 = m0 < A.n, v1 = m1 < A.n;
  if (v0) *(float4*)(A.out + (size_t)m0 * 64 + ch0) = o0;
  if (v1) *(float4*)(A.out + (size_t)m1 * 64 + ch0) = o1;

  if (A.colsum) {
    float4 sc;
    sc.x = (v0 ? o0.x : 0.f) + (v1 ? o1.x : 0.f);
    sc.y = (v0 ? o0.y : 0.f) + (v1 ? o1.y : 0.f);
    sc.z = (v0 ? o0.z : 0.f) + (v1 ? o1.z : 0.f);
    sc.w = (v0 ? o0.w : 0.f) + (v1 ? o1.w : 0.f);
    __syncthreads();                      // compute reads of sAT done (all waves)
    *(float4*)&sAT[0][ty][ch0] = sc;      // red[ty][ch]
    __syncthreads();
    if (t < 64) {
      float ssum = 0.f;
      for (int r = 0; r < 32; ++r) ssum += sAT[0][r][t];   // bank = (4r+t)%32: 2-way, free
      atomicAdd(&A.colsum[t], ssum);
    }
  }
}

// ---------------- tiny post-MLP (single block) ----------------
__global__ __launch_bounds__(256) void k_post(const float* __restrict__ s,
                                              const float* __restrict__ w1, const float* __restrict__ b1,
                                              const float* __restrict__ w2, const float* __restrict__ b2,
                                              const float* __restrict__ w3, const float* __restrict__ b3,
                                              const float* __restrict__ w4, const float* __restrict__ b4,
                                              float* __restrict__ outp) {
  __shared__ float sh[256], h1[64], h2[64], h3[256];
  int t = threadIdx.x;
  sh[t] = s[t];
  __syncthreads();
  if (t < 64) {
    float a = b1[t];
    for (int k = 0; k < 256; ++k) a += sh[k] * w1[k * 64 + t];
    h1[t] = (a >= 0.f) ? a : 0.1f * a;   // leaky_relu 0.1
  }
  __syncthreads();
  if (t < 64) {
    float a = b2[t];
    for (int k = 0; k < 64; ++k) a += h1[k] * w2[k * 64 + t];
    h2[t] = fmaxf(a, 0.f);
  }
  __syncthreads();
  {
    float a = b3[t];
    for (int k = 0; k < 64; ++k) a += h2[k] * w3[k * 256 + t];
    h3[t] = fmaxf(a, 0.f);
  }
  __syncthreads();
  if (t < 64) {
    float a = b4[t];
    for (int k = 0; k < 256; ++k) a += h3[k] * w4[k * 64 + t];
    outp[t] = a;
  }
}

extern "C" void kernel_launch(void* const* d_in, const int* in_sizes, int n_in,
                              void* d_out, int out_size, void* d_ws, size_t ws_size,
                              hipStream_t stream) {
  const float* nf     = (const float*)d_in[0];
  const int*   ei     = (const int*)d_in[1];
  const float* pre_w1 = (const float*)d_in[2];
  const float* pre_b1 = (const float*)d_in[3];
  const float* pre_w2 = (const float*)d_in[4];
  const float* pre_b2 = (const float*)d_in[5];
  const float* skip   = (const float*)d_in[6];
  const float* wl0 = (const float*)d_in[7],  *bl0 = (const float*)d_in[8],  *wr0 = (const float*)d_in[9];
  const float* wl1 = (const float*)d_in[10], *bl1 = (const float*)d_in[11], *wr1 = (const float*)d_in[12];
  const float* wl2 = (const float*)d_in[13], *bl2 = (const float*)d_in[14], *wr2 = (const float*)d_in[15];
  const float* pw1 = (const float*)d_in[16], *pb1 = (const float*)d_in[17];
  const float* pw2 = (const float*)d_in[18], *pb2 = (const float*)d_in[19];
  const float* pw3 = (const float*)d_in[20], *pb3 = (const float*)d_in[21];
  const float* pw4 = (const float*)d_in[22], *pb4 = (const float*)d_in[23];
  float* out = (float*)d_out;

  const int N = NN, E = NE;
  const int NBLK = (N + 255) / 256;   // 196

  // workspace carve-up
  char* ws = (char*)d_ws;
  size_t pos = 0;
  auto alloc = [&](size_t bytes) {
    char* p = ws + pos;
    pos += (bytes + 255) & ~(size_t)255;
    return (void*)p;
  };
  int*   cnt    = (int*)alloc((size_t)N * 4);
  int*   offs   = (int*)alloc((size_t)(N + 1) * 4);
  int*   cursor = (int*)alloc((size_t)N * 4);
  int*   csr    = (int*)alloc((size_t)E * 4);
  float* invd   = (float*)alloc((size_t)N * 4);
  int*   bsum   = (int*)alloc((size_t)NBLK * 4);
  const size_t FB = (size_t)N * 64 * 4;
  float* x  = (float*)alloc(FB);
  float* h0 = (float*)alloc(FB);
  float* h1 = (float*)alloc(FB);
  float* h2 = (float*)alloc(FB);
  float* m0 = (float*)alloc(FB);
  float* m1 = (float*)alloc(FB);
  float* m2 = (float*)alloc(FB);
  float* t0 = m2;                 // pre-MLP hidden; dead before m2 is written
  float* sv = (float*)alloc(256 * 4);

  hipMemsetAsync(cnt, 0, (size_t)N * 4, stream);
  hipMemsetAsync(sv, 0, 256 * 4, stream);

  const int* e_src = ei;
  const int* e_dst = ei + E;
  k_deg<<<(E + 255) / 256, 256, 0, stream>>>(e_dst, E, cnt);
  k_blockred<<<NBLK, 256, 0, stream>>>(cnt, N, bsum);
  k_scanb<<<1, 256, 0, stream>>>(bsum, NBLK, offs + N);   // writes offs[N] = E total
  k_scanfinal<<<NBLK, 256, 0, stream>>>(cnt, N, bsum, offs, cursor, invd);
  k_scatter<<<(E + 255) / 256, 256, 0, stream>>>(e_src, e_dst, E, cursor, csr);

  const int LGRID = (N + 63) / 64;
  auto lin = [&](int nsrc,
                 const float* a0, int s0, const float* w0, int g0,
                 const float* a1, int s1, const float* w1_, int g1,
                 const float* a2, int s2, const float* w2_, int g2,
                 const float* a3, int s3, const float* w3_, int g3,
                 const float* a4, int s4, const float* w4_, int g4,
                 const float* a5, int s5, const float* w5_, int g5,
                 const float* bias, float* outp, float* colsum, int relu) {
    LinArgs A;
    A.a[0] = a0; A.a[1] = a1; A.a[2] = a2; A.a[3] = a3; A.a[4] = a4; A.a[5] = a5;
    A.w[0] = w0; A.w[1] = w1_; A.w[2] = w2_; A.w[3] = w3_; A.w[4] = w4_; A.w[5] = w5_;
    A.gidx[0] = g0; A.gidx[1] = g1; A.gidx[2] = g2; A.gidx[3] = g3; A.gidx[4] = g4; A.gidx[5] = g5;
    A.stride[0] = s0; A.stride[1] = s1; A.stride[2] = s2; A.stride[3] = s3; A.stride[4] = s4; A.stride[5] = s5;
    A.nsrc = nsrc; A.bias = bias; A.skip = skip; A.out = outp; A.colsum = colsum;
    A.n = N; A.relu = relu;
    k_linear<<<LGRID, 512, 0, stream>>>(A);
  };

  // pre_mlp: t0 = relu(nf @ pre_w1 + pre_b1)   (K=128 -> two 64-row blocks)
  lin(2, nf, 128, pre_w1, -1, nf + 64, 128, pre_w1 + 64 * 64, -1,
      nullptr, 0, nullptr, -1, nullptr, 0, nullptr, -1, nullptr, 0, nullptr, -1,
      nullptr, 0, nullptr, -1, pre_b1, t0, nullptr, 1);
  // x = t0 @ pre_w2 + pre_b2  (fused colsum -> sv[0:64])
  lin(1, t0, 64, pre_w2, -1,
      nullptr, 0, nullptr, -1, nullptr, 0, nullptr, -1, nullptr, 0, nullptr, -1,
      nullptr, 0, nullptr, -1, nullptr, 0, nullptr, -1, pre_b2, x, sv, 0);

  // layer 0
  k_aggregate<<<(N + 3) / 4, 256, 0, stream>>>(x, offs, csr, invd, m0, N);
  lin(2, m0, 64, wl0, 0, x, 64, wr0, 0,
      nullptr, 0, nullptr, -1, nullptr, 0, nullptr, -1, nullptr, 0, nullptr, -1,
      nullptr, 0, nullptr, -1, bl0, h0, sv + 64, 1);

  // layer 1 (gates skip[1][0]=idx3, skip[1][1]=idx4)
  k_aggregate<<<(N + 3) / 4, 256, 0, stream>>>(h0, offs, csr, invd, m1, N);
  lin(4, m0, 64, wl1, 3, m1, 64, wl1 + 64 * 64, 4,
      x, 64, wr1, 3, h0, 64, wr1 + 64 * 64, 4,
      nullptr, 0, nullptr, -1, nullptr, 0, nullptr, -1, bl1, h1, sv + 128, 1);

  // layer 2 (gates skip[2][0..2] = idx 6,7,8)
  k_aggregate<<<(N + 3) / 4, 256, 0, stream>>>(h1, offs, csr, invd, m2, N);
  lin(6, m0, 64, wl2, 6, m1, 64, wl2 + 64 * 64, 7, m2, 64, wl2 + 128 * 64, 8,
      x, 64, wr2, 6, h0, 64, wr2 + 64 * 64, 7, h1, 64, wr2 + 128 * 64, 8,
      bl2, h2, sv + 192, 1);

  // post-MLP on the fused column sums
  k_post<<<1, 256, 0, stream>>>(sv, pw1, pb1, pw2, pb2, pw3, pb3, pw4, pb4, out);
}

// Round 5
// 571.069 us; speedup vs baseline: 1.0257x; 1.0257x over previous
//
#include <hip/hip_runtime.h>
#include <math.h>

#define NN 50000
#define NE 800000

// ---------------- degree count ----------------
__global__ void k_deg(const int* __restrict__ dst, int e_cnt, int* __restrict__ cnt) {
  int e = blockIdx.x * 256 + threadIdx.x;
  if (e < e_cnt) atomicAdd(&cnt[dst[e]], 1);
}

// ---------------- two-level exclusive scan ----------------
__global__ __launch_bounds__(256) void k_blockred(const int* __restrict__ cnt, int n,
                                                  int* __restrict__ bsum) {
  __shared__ int sd[256];
  int t = threadIdx.x;
  int i = blockIdx.x * 256 + t;
  sd[t] = (i < n) ? cnt[i] : 0;
  __syncthreads();
  for (int o = 128; o > 0; o >>= 1) {
    if (t < o) sd[t] += sd[t + o];
    __syncthreads();
  }
  if (t == 0) bsum[blockIdx.x] = sd[0];
}

__global__ __launch_bounds__(256) void k_scanb(int* __restrict__ bsum, int nb,
                                               int* __restrict__ total) {
  __shared__ int sd[256];
  int t = threadIdx.x;
  int v = (t < nb) ? bsum[t] : 0;
  sd[t] = v;
  __syncthreads();
  for (int o = 1; o < 256; o <<= 1) {
    int u = (t >= o) ? sd[t - o] : 0;
    __syncthreads();
    sd[t] += u;
    __syncthreads();
  }
  if (t < nb) bsum[t] = sd[t] - v;   // exclusive
  if (t == 255) *total = sd[255];
}

__global__ __launch_bounds__(256) void k_scanfinal(const int* __restrict__ cnt, int n,
                                                   const int* __restrict__ bsum,
                                                   int* __restrict__ offs,
                                                   int* __restrict__ cursor,
                                                   float* __restrict__ invd) {
  __shared__ int sd[256];
  int t = threadIdx.x;
  int i = blockIdx.x * 256 + t;
  int v = (i < n) ? cnt[i] : 0;
  sd[t] = v;
  __syncthreads();
  for (int o = 1; o < 256; o <<= 1) {
    int u = (t >= o) ? sd[t - o] : 0;
    __syncthreads();
    sd[t] += u;
    __syncthreads();
  }
  if (i < n) {
    int off = bsum[blockIdx.x] + sd[t] - v;
    offs[i]   = off;
    cursor[i] = off;
    invd[i]   = 1.0f / fmaxf((float)v, 1.0f);
  }
}

// ---------------- scatter edges into CSR ----------------
__global__ void k_scatter(const int* __restrict__ src, const int* __restrict__ dst, int e_cnt,
                          int* __restrict__ cursor, int* __restrict__ csr) {
  int e = blockIdx.x * 256 + threadIdx.x;
  if (e < e_cnt) {
    int d = dst[e];
    int p = atomicAdd(&cursor[d], 1);
    csr[p] = src[e];
  }
}

// ---------------- per-node mean aggregation ----------------
// One wave per node. lane = nsub*16 + cg; 16 neighbor rows in flight per iter.
__global__ __launch_bounds__(256) void k_aggregate(const float* __restrict__ feat,
                                                   const int* __restrict__ offs,
                                                   const int* __restrict__ csr,
                                                   const float* __restrict__ invd,
                                                   float* __restrict__ mean, int n) {
  int node = blockIdx.x * 4 + (threadIdx.x >> 6);
  int lane = threadIdx.x & 63;
  int nsub = lane >> 4;        // 0..3: neighbor sub-slot
  int cg   = lane & 15;        // 0..15: float4 channel group
  if (node >= n) return;
  int s = offs[node], e = offs[node + 1];

  float ax = 0.f, ay = 0.f, az = 0.f, aw = 0.f;
  if (e > s) {
    int emax = e - 1;
    for (int p0 = s; p0 < e; p0 += 16) {
      int pa = p0 + nsub;
      int pb = p0 + 4 + nsub;
      int pc = p0 + 8 + nsub;
      int pd = p0 + 12 + nsub;
      int ja = csr[pa < emax ? pa : emax];
      int jb = csr[pb < emax ? pb : emax];
      int jc = csr[pc < emax ? pc : emax];
      int jd = csr[pd < emax ? pd : emax];
      float4 va = *(const float4*)(feat + (size_t)ja * 64 + cg * 4);
      float4 vb = *(const float4*)(feat + (size_t)jb * 64 + cg * 4);
      float4 vc = *(const float4*)(feat + (size_t)jc * 64 + cg * 4);
      float4 vd = *(const float4*)(feat + (size_t)jd * 64 + cg * 4);
      if (pa < e) { ax += va.x; ay += va.y; az += va.z; aw += va.w; }
      if (pb < e) { ax += vb.x; ay += vb.y; az += vb.z; aw += vb.w; }
      if (pc < e) { ax += vc.x; ay += vc.y; az += vc.z; aw += vc.w; }
      if (pd < e) { ax += vd.x; ay += vd.y; az += vd.z; aw += vd.w; }
    }
  }
  ax += __shfl_xor(ax, 16, 64); ax += __shfl_xor(ax, 32, 64);
  ay += __shfl_xor(ay, 16, 64); ay += __shfl_xor(ay, 32, 64);
  az += __shfl_xor(az, 16, 64); az += __shfl_xor(az, 32, 64);
  aw += __shfl_xor(aw, 16, 64); aw += __shfl_xor(aw, 32, 64);

  if (nsub == 0) {
    float d = invd[node];
    float4 o = make_float4(ax * d, ay * d, az * d, aw * d);
    *(float4*)(mean + (size_t)node * 64 + cg * 4) = o;
  }
}

// ---------------- fused multi-source linear ----------------
// out = act( sum_s g_s * A_s @ W_s + bias ); optional fused column-sum.
// 128 threads (2 waves), 32-node tile, thread = 4 nodes x 4 ch (acc 4x4).
// A^T staged in LDS, stride 36, XOR swizzle g' = g ^ ((k>>2)&7):
//   staging writes 2-way bank (free, m136), b128 reads aligned & conflict-free.
// Double-buffered: prefetch source s+1 into regs during compute of s; ONE barrier/source.
struct LinArgs {
  const float* a[6];
  const float* w[6];
  int gidx[6];        // index into skip (flattened 3x3), or -1 => gate 1.0
  int stride[6];
  int nsrc;
  const float* bias;  // [64]
  const float* skip;  // [9]
  float* out;         // [n,64]
  float* colsum;      // [64] atomic column-sum target, or nullptr
  int n;
  int relu;
};

__global__ __launch_bounds__(128) void k_linear(LinArgs A) {
  __shared__ float sAT[2][64 * 36];  // [buf][k*36 + swizzled col]
  const int t   = threadIdx.x;       // 0..127
  const int tx  = t & 15;            // ch group (also staging col-group)
  const int ty  = t >> 4;            // 0..7 node group (also staging row group)
  const int ch0 = tx * 4;
  const int n0  = blockIdx.x * 32;

  float acc[4][4];
#pragma unroll
  for (int m = 0; m < 4; ++m)
#pragma unroll
    for (int c = 0; c < 4; ++c) acc[m][c] = 0.0f;

  // staging map: 4 float4 per thread: row = ty + 8i (0..31), cg = tx
  float4 pf[4];
  auto load_src = [&](int s) {
    const float* a  = A.a[s];
    const int    st = A.stride[s];
#pragma unroll
    for (int i = 0; i < 4; ++i) {
      int gr = n0 + ty + 8 * i;
      float4 vv = make_float4(0.f, 0.f, 0.f, 0.f);
      if (gr < A.n) vv = *(const float4*)(a + (size_t)gr * st + ch0);
      pf[i] = vv;
    }
  };
  auto write_src = [&](int s, int b) {
    float gs = 1.0f;
    if (A.gidx[s] >= 0) {
      float sv = A.skip[A.gidx[s]];
      gs = 1.0f / (1.0f + expf(-sv));
    }
    float* dst = &sAT[b][0];
#pragma unroll
    for (int i = 0; i < 4; ++i) {
      int r = ty + 8 * i;
      int g = r >> 2, ro = r & 3;
#pragma unroll
      for (int j = 0; j < 4; ++j) {
        int k  = ch0 + j;
        int gp = g ^ ((k >> 2) & 7);       // XOR swizzle
        float v = (j == 0) ? pf[i].x : (j == 1) ? pf[i].y : (j == 2) ? pf[i].z : pf[i].w;
        dst[k * 36 + gp * 4 + ro] = v * gs;
      }
    }
  };

  load_src(0);
  write_src(0, 0);
  __syncthreads();

  for (int s = 0; s < A.nsrc; ++s) {
    if (s + 1 < A.nsrc) {
      load_src(s + 1);
      write_src(s + 1, (s + 1) & 1);   // writes other buffer: no hazard w/ current reads
    }
    const float* w   = A.w[s];
    const float* buf = &sAT[s & 1][0];
#pragma unroll 4
    for (int k = 0; k < 64; ++k) {
      int gp = ty ^ ((k >> 2) & 7);
      float4 wv = *(const float4*)(w + k * 64 + ch0);
      float4 av = *(const float4*)(buf + k * 36 + gp * 4);
      acc[0][0] += av.x * wv.x; acc[0][1] += av.x * wv.y; acc[0][2] += av.x * wv.z; acc[0][3] += av.x * wv.w;
      acc[1][0] += av.y * wv.x; acc[1][1] += av.y * wv.y; acc[1][2] += av.y * wv.z; acc[1][3] += av.y * wv.w;
      acc[2][0] += av.z * wv.x; acc[2][1] += av.z * wv.y; acc[2][2] += av.z * wv.z; acc[2][3] += av.z * wv.w;
      acc[3][0] += av.w * wv.x; acc[3][1] += av.w * wv.y; acc[3][2] += av.w * wv.z; acc[3][3] += av.w * wv.w;
    }
    __syncthreads();   // next iter's compute reads buf written above
  }

  float4 bv = *(const float4*)(A.bias + ch0);
  float4 o[4];
  bool vld[4];
#pragma unroll
  for (int m = 0; m < 4; ++m) {
    int node = n0 + ty * 4 + m;
    vld[m] = node < A.n;
    o[m].x = acc[m][0] + bv.x; o[m].y = acc[m][1] + bv.y;
    o[m].z = acc[m][2] + bv.z; o[m].w = acc[m][3] + bv.w;
    if (A.relu) {
      o[m].x = fmaxf(o[m].x, 0.f); o[m].y = fmaxf(o[m].y, 0.f);
      o[m].z = fmaxf(o[m].z, 0.f); o[m].w = fmaxf(o[m].w, 0.f);
    }
    if (vld[m]) *(float4*)(A.out + (size_t)(node) * 64 + ch0) = o[m];
  }

  if (A.colsum) {
    float4 sc = make_float4(0.f, 0.f, 0.f, 0.f);
#pragma unroll
    for (int m = 0; m < 4; ++m) {
      if (vld[m]) { sc.x += o[m].x; sc.y += o[m].y; sc.z += o[m].z; sc.w += o[m].w; }
    }
    // red[ty][64 ch] in sAT[0] (stride 68 to dodge conflicts)
    float* red = &sAT[0][0];
    *(float4*)(red + ty * 68 + ch0) = sc;
    __syncthreads();
    if (t < 64) {
      float ssum = 0.f;
#pragma unroll
      for (int r = 0; r < 8; ++r) ssum += red[r * 68 + t];
      atomicAdd(&A.colsum[t], ssum);
    }
  }
}

// ---------------- tiny post-MLP (single block) ----------------
__global__ __launch_bounds__(256) void k_post(const float* __restrict__ s,
                                              const float* __restrict__ w1, const float* __restrict__ b1,
                                              const float* __restrict__ w2, const float* __restrict__ b2,
                                              const float* __restrict__ w3, const float* __restrict__ b3,
                                              const float* __restrict__ w4, const float* __restrict__ b4,
                                              float* __restrict__ outp) {
  __shared__ float sh[256], h1[64], h2[64], h3[256];
  int t = threadIdx.x;
  sh[t] = s[t];
  __syncthreads();
  if (t < 64) {
    float a = b1[t];
    for (int k = 0; k < 256; ++k) a += sh[k] * w1[k * 64 + t];
    h1[t] = (a >= 0.f) ? a : 0.1f * a;   // leaky_relu 0.1
  }
  __syncthreads();
  if (t < 64) {
    float a = b2[t];
    for (int k = 0; k < 64; ++k) a += h1[k] * w2[k * 64 + t];
    h2[t] = fmaxf(a, 0.f);
  }
  __syncthreads();
  {
    float a = b3[t];
    for (int k = 0; k < 64; ++k) a += h2[k] * w3[k * 256 + t];
    h3[t] = fmaxf(a, 0.f);
  }
  __syncthreads();
  if (t < 64) {
    float a = b4[t];
    for (int k = 0; k < 256; ++k) a += h3[k] * w4[k * 64 + t];
    outp[t] = a;
  }
}

extern "C" void kernel_launch(void* const* d_in, const int* in_sizes, int n_in,
                              void* d_out, int out_size, void* d_ws, size_t ws_size,
                              hipStream_t stream) {
  const float* nf     = (const float*)d_in[0];
  const int*   ei     = (const int*)d_in[1];
  const float* pre_w1 = (const float*)d_in[2];
  const float* pre_b1 = (const float*)d_in[3];
  const float* pre_w2 = (const float*)d_in[4];
  const float* pre_b2 = (const float*)d_in[5];
  const float* skip   = (const float*)d_in[6];
  const float* wl0 = (const float*)d_in[7],  *bl0 = (const float*)d_in[8],  *wr0 = (const float*)d_in[9];
  const float* wl1 = (const float*)d_in[10], *bl1 = (const float*)d_in[11], *wr1 = (const float*)d_in[12];
  const float* wl2 = (const float*)d_in[13], *bl2 = (const float*)d_in[14], *wr2 = (const float*)d_in[15];
  const float* pw1 = (const float*)d_in[16], *pb1 = (const float*)d_in[17];
  const float* pw2 = (const float*)d_in[18], *pb2 = (const float*)d_in[19];
  const float* pw3 = (const float*)d_in[20], *pb3 = (const float*)d_in[21];
  const float* pw4 = (const float*)d_in[22], *pb4 = (const float*)d_in[23];
  float* out = (float*)d_out;

  const int N = NN, E = NE;
  const int NBLK = (N + 255) / 256;   // 196

  // workspace carve-up
  char* ws = (char*)d_ws;
  size_t pos = 0;
  auto alloc = [&](size_t bytes) {
    char* p = ws + pos;
    pos += (bytes + 255) & ~(size_t)255;
    return (void*)p;
  };
  int*   cnt    = (int*)alloc((size_t)N * 4);
  int*   offs   = (int*)alloc((size_t)(N + 1) * 4);
  int*   cursor = (int*)alloc((size_t)N * 4);
  int*   csr    = (int*)alloc((size_t)E * 4);
  float* invd   = (float*)alloc((size_t)N * 4);
  int*   bsum   = (int*)alloc((size_t)NBLK * 4);
  const size_t FB = (size_t)N * 64 * 4;
  float* x  = (float*)alloc(FB);
  float* h0 = (float*)alloc(FB);
  float* h1 = (float*)alloc(FB);
  float* h2 = (float*)alloc(FB);
  float* m0 = (float*)alloc(FB);
  float* m1 = (float*)alloc(FB);
  float* m2 = (float*)alloc(FB);
  float* t0 = m2;                 // pre-MLP hidden; dead before m2 is written
  float* sv = (float*)alloc(256 * 4);

  hipMemsetAsync(cnt, 0, (size_t)N * 4, stream);
  hipMemsetAsync(sv, 0, 256 * 4, stream);

  const int* e_src = ei;
  const int* e_dst = ei + E;
  k_deg<<<(E + 255) / 256, 256, 0, stream>>>(e_dst, E, cnt);
  k_blockred<<<NBLK, 256, 0, stream>>>(cnt, N, bsum);
  k_scanb<<<1, 256, 0, stream>>>(bsum, NBLK, offs + N);   // writes offs[N] = E total
  k_scanfinal<<<NBLK, 256, 0, stream>>>(cnt, N, bsum, offs, cursor, invd);
  k_scatter<<<(E + 255) / 256, 256, 0, stream>>>(e_src, e_dst, E, cursor, csr);

  const int LGRID = (N + 31) / 32;   // 1563
  auto lin = [&](int nsrc,
                 const float* a0, int s0, const float* w0, int g0,
                 const float* a1, int s1, const float* w1_, int g1,
                 const float* a2, int s2, const float* w2_, int g2,
                 const float* a3, int s3, const float* w3_, int g3,
                 const float* a4, int s4, const float* w4_, int g4,
                 const float* a5, int s5, const float* w5_, int g5,
                 const float* bias, float* outp, float* colsum, int relu) {
    LinArgs A;
    A.a[0] = a0; A.a[1] = a1; A.a[2] = a2; A.a[3] = a3; A.a[4] = a4; A.a[5] = a5;
    A.w[0] = w0; A.w[1] = w1_; A.w[2] = w2_; A.w[3] = w3_; A.w[4] = w4_; A.w[5] = w5_;
    A.gidx[0] = g0; A.gidx[1] = g1; A.gidx[2] = g2; A.gidx[3] = g3; A.gidx[4] = g4; A.gidx[5] = g5;
    A.stride[0] = s0; A.stride[1] = s1; A.stride[2] = s2; A.stride[3] = s3; A.stride[4] = s4; A.stride[5] = s5;
    A.nsrc = nsrc; A.bias = bias; A.skip = skip; A.out = outp; A.colsum = colsum;
    A.n = N; A.relu = relu;
    k_linear<<<LGRID, 128, 0, stream>>>(A);
  };

  // pre_mlp: t0 = relu(nf @ pre_w1 + pre_b1)   (K=128 -> two 64-row blocks)
  lin(2, nf, 128, pre_w1, -1, nf + 64, 128, pre_w1 + 64 * 64, -1,
      nullptr, 0, nullptr, -1, nullptr, 0, nullptr, -1, nullptr, 0, nullptr, -1,
      nullptr, 0, nullptr, -1, pre_b1, t0, nullptr, 1);
  // x = t0 @ pre_w2 + pre_b2  (fused colsum -> sv[0:64])
  lin(1, t0, 64, pre_w2, -1,
      nullptr, 0, nullptr, -1, nullptr, 0, nullptr, -1, nullptr, 0, nullptr, -1,
      nullptr, 0, nullptr, -1, nullptr, 0, nullptr, -1, pre_b2, x, sv, 0);

  // layer 0
  k_aggregate<<<(N + 3) / 4, 256, 0, stream>>>(x, offs, csr, invd, m0, N);
  lin(2, m0, 64, wl0, 0, x, 64, wr0, 0,
      nullptr, 0, nullptr, -1, nullptr, 0, nullptr, -1, nullptr, 0, nullptr, -1,
      nullptr, 0, nullptr, -1, bl0, h0, sv + 64, 1);

  // layer 1 (gates skip[1][0]=idx3, skip[1][1]=idx4)
  k_aggregate<<<(N + 3) / 4, 256, 0, stream>>>(h0, offs, csr, invd, m1, N);
  lin(4, m0, 64, wl1, 3, m1, 64, wl1 + 64 * 64, 4,
      x, 64, wr1, 3, h0, 64, wr1 + 64 * 64, 4,
      nullptr, 0, nullptr, -1, nullptr, 0, nullptr, -1, bl1, h1, sv + 128, 1);

  // layer 2 (gates skip[2][0..2] = idx 6,7,8)
  k_aggregate<<<(N + 3) / 4, 256, 0, stream>>>(h1, offs, csr, invd, m2, N);
  lin(6, m0, 64, wl2, 6, m1, 64, wl2 + 64 * 64, 7, m2, 64, wl2 + 128 * 64, 8,
      x, 64, wr2, 6, h0, 64, wr2 + 64 * 64, 7, h1, 64, wr2 + 128 * 64, 8,
      bl2, h2, sv + 192, 1);

  // post-MLP on the fused column sums
  k_post<<<1, 256, 0, stream>>>(sv, pw1, pb1, pw2, pb2, pw3, pb3, pw4, pb4, out);
}

// Round 6
// 525.707 us; speedup vs baseline: 1.1142x; 1.0863x over previous
//
#include <hip/hip_runtime.h>
#include <math.h>

#define NN 50000
#define NE 800000

// ---------------- degree count ----------------
__global__ void k_deg(const int* __restrict__ dst, int e_cnt, int* __restrict__ cnt) {
  int e = blockIdx.x * 256 + threadIdx.x;
  if (e < e_cnt) atomicAdd(&cnt[dst[e]], 1);
}

// ---------------- two-level exclusive scan ----------------
__global__ __launch_bounds__(256) void k_blockred(const int* __restrict__ cnt, int n,
                                                  int* __restrict__ bsum) {
  __shared__ int sd[256];
  int t = threadIdx.x;
  int i = blockIdx.x * 256 + t;
  sd[t] = (i < n) ? cnt[i] : 0;
  __syncthreads();
  for (int o = 128; o > 0; o >>= 1) {
    if (t < o) sd[t] += sd[t + o];
    __syncthreads();
  }
  if (t == 0) bsum[blockIdx.x] = sd[0];
}

__global__ __launch_bounds__(256) void k_scanb(int* __restrict__ bsum, int nb,
                                               int* __restrict__ total) {
  __shared__ int sd[256];
  int t = threadIdx.x;
  int v = (t < nb) ? bsum[t] : 0;
  sd[t] = v;
  __syncthreads();
  for (int o = 1; o < 256; o <<= 1) {
    int u = (t >= o) ? sd[t - o] : 0;
    __syncthreads();
    sd[t] += u;
    __syncthreads();
  }
  if (t < nb) bsum[t] = sd[t] - v;   // exclusive
  if (t == 255) *total = sd[255];
}

__global__ __launch_bounds__(256) void k_scanfinal(const int* __restrict__ cnt, int n,
                                                   const int* __restrict__ bsum,
                                                   int* __restrict__ offs,
                                                   int* __restrict__ cursor,
                                                   float* __restrict__ invd) {
  __shared__ int sd[256];
  int t = threadIdx.x;
  int i = blockIdx.x * 256 + t;
  int v = (i < n) ? cnt[i] : 0;
  sd[t] = v;
  __syncthreads();
  for (int o = 1; o < 256; o <<= 1) {
    int u = (t >= o) ? sd[t - o] : 0;
    __syncthreads();
    sd[t] += u;
    __syncthreads();
  }
  if (i < n) {
    int off = bsum[blockIdx.x] + sd[t] - v;
    offs[i]   = off;
    cursor[i] = off;
    invd[i]   = 1.0f / fmaxf((float)v, 1.0f);
  }
}

// ---------------- scatter edges into CSR ----------------
__global__ void k_scatter(const int* __restrict__ src, const int* __restrict__ dst, int e_cnt,
                          int* __restrict__ cursor, int* __restrict__ csr) {
  int e = blockIdx.x * 256 + threadIdx.x;
  if (e < e_cnt) {
    int d = dst[e];
    int p = atomicAdd(&cursor[d], 1);
    csr[p] = src[e];
  }
}

// ---------------- per-node mean aggregation ----------------
// One wave per node. lane = nsub*16 + cg; 16 neighbor rows in flight per iter.
__global__ __launch_bounds__(256) void k_aggregate(const float* __restrict__ feat,
                                                   const int* __restrict__ offs,
                                                   const int* __restrict__ csr,
                                                   const float* __restrict__ invd,
                                                   float* __restrict__ mean, int n) {
  int node = blockIdx.x * 4 + (threadIdx.x >> 6);
  int lane = threadIdx.x & 63;
  int nsub = lane >> 4;        // 0..3: neighbor sub-slot
  int cg   = lane & 15;        // 0..15: float4 channel group
  if (node >= n) return;
  int s = offs[node], e = offs[node + 1];

  float ax = 0.f, ay = 0.f, az = 0.f, aw = 0.f;
  if (e > s) {
    int emax = e - 1;
    for (int p0 = s; p0 < e; p0 += 16) {
      int pa = p0 + nsub;
      int pb = p0 + 4 + nsub;
      int pc = p0 + 8 + nsub;
      int pd = p0 + 12 + nsub;
      int ja = csr[pa < emax ? pa : emax];
      int jb = csr[pb < emax ? pb : emax];
      int jc = csr[pc < emax ? pc : emax];
      int jd = csr[pd < emax ? pd : emax];
      float4 va = *(const float4*)(feat + (size_t)ja * 64 + cg * 4);
      float4 vb = *(const float4*)(feat + (size_t)jb * 64 + cg * 4);
      float4 vc = *(const float4*)(feat + (size_t)jc * 64 + cg * 4);
      float4 vd = *(const float4*)(feat + (size_t)jd * 64 + cg * 4);
      if (pa < e) { ax += va.x; ay += va.y; az += va.z; aw += va.w; }
      if (pb < e) { ax += vb.x; ay += vb.y; az += vb.z; aw += vb.w; }
      if (pc < e) { ax += vc.x; ay += vc.y; az += vc.z; aw += vc.w; }
      if (pd < e) { ax += vd.x; ay += vd.y; az += vd.z; aw += vd.w; }
    }
  }
  ax += __shfl_xor(ax, 16, 64); ax += __shfl_xor(ax, 32, 64);
  ay += __shfl_xor(ay, 16, 64); ay += __shfl_xor(ay, 32, 64);
  az += __shfl_xor(az, 16, 64); az += __shfl_xor(az, 32, 64);
  aw += __shfl_xor(aw, 16, 64); aw += __shfl_xor(aw, 32, 64);

  if (nsub == 0) {
    float d = invd[node];
    float4 o = make_float4(ax * d, ay * d, az * d, aw * d);
    *(float4*)(mean + (size_t)node * 64 + cg * 4) = o;
  }
}

// ---------------- fused multi-source linear ----------------
// out = act( sum_s g_s * A_s @ W_s + bias ); optional fused column-sum.
// 256 threads (4 waves), 64-node tile, thread = 4 nodes x 4 ch (acc 4x4 — R3 shape).
// A^T staged in LDS stride 68 with XOR swizzle g' = g ^ ((k>>2)&15):
//   staging writes hit all 32 banks 2-way (free), compute reads are broadcasts.
// Pipeline per source: load(s+1) -> compute(s) -> write(s+1) -> barrier (R4 ordering:
//   global latency hides under the 64-iter FMA stream; ONE barrier per source).
struct LinArgs {
  const float* a[6];
  const float* w[6];
  int gidx[6];        // index into skip (flattened 3x3), or -1 => gate 1.0
  int stride[6];
  int nsrc;
  const float* bias;  // [64]
  const float* skip;  // [9]
  float* out;         // [n,64]
  float* colsum;      // [64] atomic column-sum target, or nullptr
  int n;
  int relu;
};

__global__ __launch_bounds__(256) void k_linear(LinArgs A) {
  __shared__ float sAT[2][64 * 68];  // [buf][k*68 + 4*swizzled_group + row&3]
  const int t   = threadIdx.x;       // 0..255
  const int tx  = t & 15;            // ch group (staging: k-group; compute: out-ch group)
  const int ty  = t >> 4;            // 0..15 (staging: row group; compute: node group)
  const int ch0 = tx * 4;
  const int n0  = blockIdx.x * 64;

  float acc[4][4];
#pragma unroll
  for (int m = 0; m < 4; ++m)
#pragma unroll
    for (int c = 0; c < 4; ++c) acc[m][c] = 0.0f;

  // staging map: 4 float4/thread: row r = ty + 16*i, channels ch0..ch0+3
  float4 pf[4];
  auto load_src = [&](int s) {
    const float* a  = A.a[s];
    const int    st = A.stride[s];
#pragma unroll
    for (int i = 0; i < 4; ++i) {
      int gr = n0 + ty + 16 * i;
      float4 vv = make_float4(0.f, 0.f, 0.f, 0.f);
      if (gr < A.n) vv = *(const float4*)(a + (size_t)gr * st + ch0);
      pf[i] = vv;
    }
  };
  auto write_src = [&](int s, int b) {
    float gs = 1.0f;
    if (A.gidx[s] >= 0) {
      float sv = A.skip[A.gidx[s]];
      gs = 1.0f / (1.0f + expf(-sv));
    }
    float* dst = &sAT[b][0];
#pragma unroll
    for (int i = 0; i < 4; ++i) {
      int r  = ty + 16 * i;
      int g  = r >> 2, ro = r & 3;
      int gp = g ^ tx;                  // swz(k) = (k>>2)&15 = tx for k = 4tx+j
#pragma unroll
      for (int j = 0; j < 4; ++j) {
        int k = ch0 + j;
        float v = (j == 0) ? pf[i].x : (j == 1) ? pf[i].y : (j == 2) ? pf[i].z : pf[i].w;
        dst[k * 68 + gp * 4 + ro] = v * gs;
      }
    }
  };

  load_src(0);
  write_src(0, 0);
  __syncthreads();

  for (int s = 0; s < A.nsrc; ++s) {
    if (s + 1 < A.nsrc) load_src(s + 1);   // prefetch: vmcnt waits land in write_src below
    const float* w   = A.w[s];
    const float* buf = &sAT[s & 1][0];
#pragma unroll 4
    for (int k = 0; k < 64; ++k) {
      int gp = ty ^ (k >> 2);
      float4 wv = *(const float4*)(w + k * 64 + ch0);
      float4 av = *(const float4*)(buf + k * 68 + gp * 4);
      acc[0][0] += av.x * wv.x; acc[0][1] += av.x * wv.y; acc[0][2] += av.x * wv.z; acc[0][3] += av.x * wv.w;
      acc[1][0] += av.y * wv.x; acc[1][1] += av.y * wv.y; acc[1][2] += av.y * wv.z; acc[1][3] += av.y * wv.w;
      acc[2][0] += av.z * wv.x; acc[2][1] += av.z * wv.y; acc[2][2] += av.z * wv.z; acc[2][3] += av.z * wv.w;
      acc[3][0] += av.w * wv.x; acc[3][1] += av.w * wv.y; acc[3][2] += av.w * wv.z; acc[3][3] += av.w * wv.w;
    }
    if (s + 1 < A.nsrc) write_src(s + 1, (s + 1) & 1);  // other buffer: no read hazard
    __syncthreads();
  }

  float4 bv = *(const float4*)(A.bias + ch0);
  float4 o[4];
  bool vld[4];
#pragma unroll
  for (int m = 0; m < 4; ++m) {
    int node = n0 + ty * 4 + m;
    vld[m] = node < A.n;
    o[m].x = acc[m][0] + bv.x; o[m].y = acc[m][1] + bv.y;
    o[m].z = acc[m][2] + bv.z; o[m].w = acc[m][3] + bv.w;
    if (A.relu) {
      o[m].x = fmaxf(o[m].x, 0.f); o[m].y = fmaxf(o[m].y, 0.f);
      o[m].z = fmaxf(o[m].z, 0.f); o[m].w = fmaxf(o[m].w, 0.f);
    }
    if (vld[m]) *(float4*)(A.out + (size_t)node * 64 + ch0) = o[m];
  }

  if (A.colsum) {
    float4 sc = make_float4(0.f, 0.f, 0.f, 0.f);
#pragma unroll
    for (int m = 0; m < 4; ++m) {
      if (vld[m]) { sc.x += o[m].x; sc.y += o[m].y; sc.z += o[m].z; sc.w += o[m].w; }
    }
    // loop ended with a barrier, sAT[0] is free to reuse
    float* red = &sAT[0][0];
    *(float4*)(red + ty * 68 + ch0) = sc;   // red[ty][ch], stride 68
    __syncthreads();
    if (t < 64) {
      float ssum = 0.f;
#pragma unroll
      for (int r = 0; r < 16; ++r) ssum += red[r * 68 + t];  // 2-way bank: free
      atomicAdd(&A.colsum[t], ssum);
    }
  }
}

// ---------------- tiny post-MLP (single block) ----------------
__global__ __launch_bounds__(256) void k_post(const float* __restrict__ s,
                                              const float* __restrict__ w1, const float* __restrict__ b1,
                                              const float* __restrict__ w2, const float* __restrict__ b2,
                                              const float* __restrict__ w3, const float* __restrict__ b3,
                                              const float* __restrict__ w4, const float* __restrict__ b4,
                                              float* __restrict__ outp) {
  __shared__ float sh[256], h1[64], h2[64], h3[256];
  int t = threadIdx.x;
  sh[t] = s[t];
  __syncthreads();
  if (t < 64) {
    float a = b1[t];
    for (int k = 0; k < 256; ++k) a += sh[k] * w1[k * 64 + t];
    h1[t] = (a >= 0.f) ? a : 0.1f * a;   // leaky_relu 0.1
  }
  __syncthreads();
  if (t < 64) {
    float a = b2[t];
    for (int k = 0; k < 64; ++k) a += h1[k] * w2[k * 64 + t];
    h2[t] = fmaxf(a, 0.f);
  }
  __syncthreads();
  {
    float a = b3[t];
    for (int k = 0; k < 64; ++k) a += h2[k] * w3[k * 256 + t];
    h3[t] = fmaxf(a, 0.f);
  }
  __syncthreads();
  if (t < 64) {
    float a = b4[t];
    for (int k = 0; k < 256; ++k) a += h3[k] * w4[k * 64 + t];
    outp[t] = a;
  }
}

extern "C" void kernel_launch(void* const* d_in, const int* in_sizes, int n_in,
                              void* d_out, int out_size, void* d_ws, size_t ws_size,
                              hipStream_t stream) {
  const float* nf     = (const float*)d_in[0];
  const int*   ei     = (const int*)d_in[1];
  const float* pre_w1 = (const float*)d_in[2];
  const float* pre_b1 = (const float*)d_in[3];
  const float* pre_w2 = (const float*)d_in[4];
  const float* pre_b2 = (const float*)d_in[5];
  const float* skip   = (const float*)d_in[6];
  const float* wl0 = (const float*)d_in[7],  *bl0 = (const float*)d_in[8],  *wr0 = (const float*)d_in[9];
  const float* wl1 = (const float*)d_in[10], *bl1 = (const float*)d_in[11], *wr1 = (const float*)d_in[12];
  const float* wl2 = (const float*)d_in[13], *bl2 = (const float*)d_in[14], *wr2 = (const float*)d_in[15];
  const float* pw1 = (const float*)d_in[16], *pb1 = (const float*)d_in[17];
  const float* pw2 = (const float*)d_in[18], *pb2 = (const float*)d_in[19];
  const float* pw3 = (const float*)d_in[20], *pb3 = (const float*)d_in[21];
  const float* pw4 = (const float*)d_in[22], *pb4 = (const float*)d_in[23];
  float* out = (float*)d_out;

  const int N = NN, E = NE;
  const int NBLK = (N + 255) / 256;   // 196

  // workspace carve-up
  char* ws = (char*)d_ws;
  size_t pos = 0;
  auto alloc = [&](size_t bytes) {
    char* p = ws + pos;
    pos += (bytes + 255) & ~(size_t)255;
    return (void*)p;
  };
  int*   cnt    = (int*)alloc((size_t)N * 4);
  int*   offs   = (int*)alloc((size_t)(N + 1) * 4);
  int*   cursor = (int*)alloc((size_t)N * 4);
  int*   csr    = (int*)alloc((size_t)E * 4);
  float* invd   = (float*)alloc((size_t)N * 4);
  int*   bsum   = (int*)alloc((size_t)NBLK * 4);
  const size_t FB = (size_t)N * 64 * 4;
  float* x  = (float*)alloc(FB);
  float* h0 = (float*)alloc(FB);
  float* h1 = (float*)alloc(FB);
  float* h2 = (float*)alloc(FB);
  float* m0 = (float*)alloc(FB);
  float* m1 = (float*)alloc(FB);
  float* m2 = (float*)alloc(FB);
  float* t0 = m2;                 // pre-MLP hidden; dead before m2 is written
  float* sv = (float*)alloc(256 * 4);

  hipMemsetAsync(cnt, 0, (size_t)N * 4, stream);
  hipMemsetAsync(sv, 0, 256 * 4, stream);

  const int* e_src = ei;
  const int* e_dst = ei + E;
  k_deg<<<(E + 255) / 256, 256, 0, stream>>>(e_dst, E, cnt);
  k_blockred<<<NBLK, 256, 0, stream>>>(cnt, N, bsum);
  k_scanb<<<1, 256, 0, stream>>>(bsum, NBLK, offs + N);   // writes offs[N] = E total
  k_scanfinal<<<NBLK, 256, 0, stream>>>(cnt, N, bsum, offs, cursor, invd);
  k_scatter<<<(E + 255) / 256, 256, 0, stream>>>(e_src, e_dst, E, cursor, csr);

  const int LGRID = (N + 63) / 64;   // 782
  auto lin = [&](int nsrc,
                 const float* a0, int s0, const float* w0, int g0,
                 const float* a1, int s1, const float* w1_, int g1,
                 const float* a2, int s2, const float* w2_, int g2,
                 const float* a3, int s3, const float* w3_, int g3,
                 const float* a4, int s4, const float* w4_, int g4,
                 const float* a5, int s5, const float* w5_, int g5,
                 const float* bias, float* outp, float* colsum, int relu) {
    LinArgs A;
    A.a[0] = a0; A.a[1] = a1; A.a[2] = a2; A.a[3] = a3; A.a[4] = a4; A.a[5] = a5;
    A.w[0] = w0; A.w[1] = w1_; A.w[2] = w2_; A.w[3] = w3_; A.w[4] = w4_; A.w[5] = w5_;
    A.gidx[0] = g0; A.gidx[1] = g1; A.gidx[2] = g2; A.gidx[3] = g3; A.gidx[4] = g4; A.gidx[5] = g5;
    A.stride[0] = s0; A.stride[1] = s1; A.stride[2] = s2; A.stride[3] = s3; A.stride[4] = s4; A.stride[5] = s5;
    A.nsrc = nsrc; A.bias = bias; A.skip = skip; A.out = outp; A.colsum = colsum;
    A.n = N; A.relu = relu;
    k_linear<<<LGRID, 256, 0, stream>>>(A);
  };

  // pre_mlp: t0 = relu(nf @ pre_w1 + pre_b1)   (K=128 -> two 64-row blocks)
  lin(2, nf, 128, pre_w1, -1, nf + 64, 128, pre_w1 + 64 * 64, -1,
      nullptr, 0, nullptr, -1, nullptr, 0, nullptr, -1, nullptr, 0, nullptr, -1,
      nullptr, 0, nullptr, -1, pre_b1, t0, nullptr, 1);
  // x = t0 @ pre_w2 + pre_b2  (fused colsum -> sv[0:64])
  lin(1, t0, 64, pre_w2, -1,
      nullptr, 0, nullptr, -1, nullptr, 0, nullptr, -1, nullptr, 0, nullptr, -1,
      nullptr, 0, nullptr, -1, nullptr, 0, nullptr, -1, pre_b2, x, sv, 0);

  // layer 0
  k_aggregate<<<(N + 3) / 4, 256, 0, stream>>>(x, offs, csr, invd, m0, N);
  lin(2, m0, 64, wl0, 0, x, 64, wr0, 0,
      nullptr, 0, nullptr, -1, nullptr, 0, nullptr, -1, nullptr, 0, nullptr, -1,
      nullptr, 0, nullptr, -1, bl0, h0, sv + 64, 1);

  // layer 1 (gates skip[1][0]=idx3, skip[1][1]=idx4)
  k_aggregate<<<(N + 3) / 4, 256, 0, stream>>>(h0, offs, csr, invd, m1, N);
  lin(4, m0, 64, wl1, 3, m1, 64, wl1 + 64 * 64, 4,
      x, 64, wr1, 3, h0, 64, wr1 + 64 * 64, 4,
      nullptr, 0, nullptr, -1, nullptr, 0, nullptr, -1, bl1, h1, sv + 128, 1);

  // layer 2 (gates skip[2][0..2] = idx 6,7,8)
  k_aggregate<<<(N + 3) / 4, 256, 0, stream>>>(h1, offs, csr, invd, m2, N);
  lin(6, m0, 64, wl2, 6, m1, 64, wl2 + 64 * 64, 7, m2, 64, wl2 + 128 * 64, 8,
      x, 64, wr2, 6, h0, 64, wr2 + 64 * 64, 7, h1, 64, wr2 + 128 * 64, 8,
      bl2, h2, sv + 192, 1);

  // post-MLP on the fused column sums
  k_post<<<1, 256, 0, stream>>>(sv, pw1, pb1, pw2, pb2, pw3, pb3, pw4, pb4, out);
}

// Round 7
// 450.932 us; speedup vs baseline: 1.2989x; 1.1658x over previous
//
#include <hip/hip_runtime.h>
#include <math.h>

#define NN 50000
#define NE 800000

typedef float v4f __attribute__((ext_vector_type(4)));
typedef short v8s __attribute__((ext_vector_type(8)));

__device__ __forceinline__ unsigned short f2bf(float f) {
  unsigned u = __float_as_uint(f);
  u = u + 0x7FFFu + ((u >> 16) & 1u);
  return (unsigned short)(u >> 16);
}
__device__ __forceinline__ float bf2f(unsigned short h) {
  return __uint_as_float(((unsigned)h) << 16);
}

// ---------------- degree count ----------------
__global__ void k_deg(const int* __restrict__ dst, int e_cnt, int* __restrict__ cnt) {
  int e = blockIdx.x * 256 + threadIdx.x;
  if (e < e_cnt) atomicAdd(&cnt[dst[e]], 1);
}

// ---------------- two-level exclusive scan ----------------
__global__ __launch_bounds__(256) void k_blockred(const int* __restrict__ cnt, int n,
                                                  int* __restrict__ bsum) {
  __shared__ int sd[256];
  int t = threadIdx.x;
  int i = blockIdx.x * 256 + t;
  sd[t] = (i < n) ? cnt[i] : 0;
  __syncthreads();
  for (int o = 128; o > 0; o >>= 1) {
    if (t < o) sd[t] += sd[t + o];
    __syncthreads();
  }
  if (t == 0) bsum[blockIdx.x] = sd[0];
}

__global__ __launch_bounds__(256) void k_scanb(int* __restrict__ bsum, int nb,
                                               int* __restrict__ total) {
  __shared__ int sd[256];
  int t = threadIdx.x;
  int v = (t < nb) ? bsum[t] : 0;
  sd[t] = v;
  __syncthreads();
  for (int o = 1; o < 256; o <<= 1) {
    int u = (t >= o) ? sd[t - o] : 0;
    __syncthreads();
    sd[t] += u;
    __syncthreads();
  }
  if (t < nb) bsum[t] = sd[t] - v;   // exclusive
  if (t == 255) *total = sd[255];
}

__global__ __launch_bounds__(256) void k_scanfinal(const int* __restrict__ cnt, int n,
                                                   const int* __restrict__ bsum,
                                                   int* __restrict__ offs,
                                                   int* __restrict__ cursor,
                                                   float* __restrict__ invd) {
  __shared__ int sd[256];
  int t = threadIdx.x;
  int i = blockIdx.x * 256 + t;
  int v = (i < n) ? cnt[i] : 0;
  sd[t] = v;
  __syncthreads();
  for (int o = 1; o < 256; o <<= 1) {
    int u = (t >= o) ? sd[t - o] : 0;
    __syncthreads();
    sd[t] += u;
    __syncthreads();
  }
  if (i < n) {
    int off = bsum[blockIdx.x] + sd[t] - v;
    offs[i]   = off;
    cursor[i] = off;
    invd[i]   = 1.0f / fmaxf((float)v, 1.0f);
  }
}

// ---------------- scatter edges into CSR ----------------
__global__ void k_scatter(const int* __restrict__ src, const int* __restrict__ dst, int e_cnt,
                          int* __restrict__ cursor, int* __restrict__ csr) {
  int e = blockIdx.x * 256 + threadIdx.x;
  if (e < e_cnt) {
    int d = dst[e];
    int p = atomicAdd(&cursor[d], 1);
    csr[p] = src[e];
  }
}

// ---------------- per-node mean aggregation (bf16 hi/lo planes) ----------------
// One wave per node. lane = nsub*8 + cg (8 neighbor slots x 8-ch groups);
// 16 rows in flight (2-deep unroll). hi+lo summed in fp32 (no precision loss).
__global__ __launch_bounds__(256) void k_aggregate(
    const unsigned short* __restrict__ fh, const unsigned short* __restrict__ fl,
    const int* __restrict__ offs, const int* __restrict__ csr,
    const float* __restrict__ invd,
    unsigned short* __restrict__ mh, unsigned short* __restrict__ ml, int n) {
  int node = blockIdx.x * 4 + (threadIdx.x >> 6);
  int lane = threadIdx.x & 63;
  int nsub = lane >> 3;     // 0..7
  int cg   = lane & 7;      // 8 channels per lane
  if (node >= n) return;
  int s = offs[node], e = offs[node + 1];

  float a[8];
#pragma unroll
  for (int i = 0; i < 8; ++i) a[i] = 0.f;

  if (e > s) {
    int emax = e - 1;
    for (int p0 = s; p0 < e; p0 += 16) {
      int p1 = p0 + nsub, p2 = p0 + 8 + nsub;
      int j1 = csr[p1 < emax ? p1 : emax];
      int j2 = csr[p2 < emax ? p2 : emax];
      v8s h1 = *(const v8s*)(fh + (size_t)j1 * 64 + cg * 8);
      v8s l1 = *(const v8s*)(fl + (size_t)j1 * 64 + cg * 8);
      v8s h2 = *(const v8s*)(fh + (size_t)j2 * 64 + cg * 8);
      v8s l2 = *(const v8s*)(fl + (size_t)j2 * 64 + cg * 8);
      if (p1 < e) {
#pragma unroll
        for (int i = 0; i < 8; ++i)
          a[i] += bf2f((unsigned short)h1[i]) + bf2f((unsigned short)l1[i]);
      }
      if (p2 < e) {
#pragma unroll
        for (int i = 0; i < 8; ++i)
          a[i] += bf2f((unsigned short)h2[i]) + bf2f((unsigned short)l2[i]);
      }
    }
  }
#pragma unroll
  for (int i = 0; i < 8; ++i) {
    a[i] += __shfl_xor(a[i], 8, 64);
    a[i] += __shfl_xor(a[i], 16, 64);
    a[i] += __shfl_xor(a[i], 32, 64);
  }
  if (nsub == 0) {
    float d = invd[node];
    v8s oh, ol;
#pragma unroll
    for (int i = 0; i < 8; ++i) {
      float m = a[i] * d;
      unsigned short h = f2bf(m);
      oh[i] = (short)h;
      ol[i] = (short)f2bf(m - bf2f(h));
    }
    *(v8s*)(mh + (size_t)node * 64 + cg * 8) = oh;
    *(v8s*)(ml + (size_t)node * 64 + cg * 8) = ol;
  }
}

// ---------------- fused multi-source linear, MFMA split-bf16 ----------------
// out = act( sum_s A_s @ (g_s W_s) + bias ), exact to ~2^-17 via hi/lo split:
//   A = Ah+Al (bf16 planes), W = Wh+Wl; product = AhWh + AlWh + AhWl (3 MFMAs).
// 256 thr = 4 waves; tile 64 nodes x 64 ch; wave = 16-row block, 4 col-tiles.
// W^T staged in LDS [n][72 bf16] (144B stride: 2-way banks = free); gates folded
// into W at staging. Per source: loadW(s+1) -> loadA(s) -> MFMA -> writeW(s+1)
// -> barrier (R4 ordering: prefetch latency hides under compute).
struct LinArgs {
  const void*  a[6];       // fp32 ptr (isf32) or bf16 hi-plane ptr
  const float* w[6];       // [64][64] fp32 blocks (row stride 64)
  int gidx[6];             // index into skip, or -1 => gate 1.0
  int stride[6];           // fp32 row stride (fp32 sources only)
  int isf32[6];
  size_t plane_off;        // lo = hi + plane_off (ushort units)
  int nsrc;
  const float* bias;       // [64]
  const float* skip;       // [9]
  unsigned short* outh;    // hi plane [n][64]
  unsigned short* outl;    // lo plane
  float* colsum;           // [64] atomic target, or nullptr
  int n;
  int relu;
};

__global__ __launch_bounds__(256) void k_linear(LinArgs A) {
  __shared__ unsigned short sW[2][2][64 * 72];   // [buf][hi/lo][n*72+k]  36864 B
  const int t    = threadIdx.x;
  const int lane = t & 63;
  const int wv   = t >> 6;        // wave id = row-block
  const int qd   = lane >> 4;     // quad
  const int ln   = lane & 15;
  const int n0   = blockIdx.x * 64;

  v4f acc[4];
#pragma unroll
  for (int ct = 0; ct < 4; ++ct) acc[ct] = (v4f){0.f, 0.f, 0.f, 0.f};

  // ---- W staging: thread -> n = t&63, k-chunks (wv, wv+4) of 8 ----
  const int sn = t & 63;
  float wreg[16];
  auto loadW = [&](int s) {
    const float* w = A.w[s];
#pragma unroll
    for (int c = 0; c < 2; ++c) {
      int kb = (wv + 4 * c) * 8;
#pragma unroll
      for (int j = 0; j < 8; ++j)
        wreg[c * 8 + j] = w[(size_t)(kb + j) * 64 + sn];   // coalesced 256B rows
    }
  };
  auto writeW = [&](int s, int b) {
    float gs = 1.0f;
    if (A.gidx[s] >= 0) gs = 1.0f / (1.0f + __expf(-A.skip[A.gidx[s]]));
#pragma unroll
    for (int c = 0; c < 2; ++c) {
      int cb = wv + 4 * c;
      v8s hv, lv;
#pragma unroll
      for (int j = 0; j < 8; ++j) {
        float f = wreg[c * 8 + j] * gs;
        unsigned short h = f2bf(f);
        hv[j] = (short)h;
        lv[j] = (short)f2bf(f - bf2f(h));
      }
      *(v8s*)(&sW[b][0][sn * 72 + cb * 8]) = hv;   // two b128 writes per plane
      *(v8s*)(&sW[b][1][sn * 72 + cb * 8]) = lv;
    }
  };

  // ---- A fragments: row m = lane&15, k = qd*8..+7 per K-step ----
  const int arow = n0 + wv * 16 + ln;
  const bool arv = arow < A.n;
  v8s ah[2], al[2];
  auto loadA = [&](int s) {
    if (A.isf32[s]) {
      const float* a = (const float*)A.a[s];
      int st = A.stride[s];
#pragma unroll
      for (int ks = 0; ks < 2; ++ks) {
        float f[8];
        if (arv) {
          const float* p = a + (size_t)arow * st + ks * 32 + qd * 8;
          float4 u0 = *(const float4*)(p);
          float4 u1 = *(const float4*)(p + 4);
          f[0] = u0.x; f[1] = u0.y; f[2] = u0.z; f[3] = u0.w;
          f[4] = u1.x; f[5] = u1.y; f[6] = u1.z; f[7] = u1.w;
        } else {
#pragma unroll
          for (int j = 0; j < 8; ++j) f[j] = 0.f;
        }
        v8s hv, lv;
#pragma unroll
        for (int j = 0; j < 8; ++j) {
          unsigned short h = f2bf(f[j]);
          hv[j] = (short)h;
          lv[j] = (short)f2bf(f[j] - bf2f(h));
        }
        ah[ks] = hv; al[ks] = lv;
      }
    } else {
      const unsigned short* ph = (const unsigned short*)A.a[s];
      const unsigned short* pl = ph + A.plane_off;
      if (arv) {
#pragma unroll
        for (int ks = 0; ks < 2; ++ks) {
          ah[ks] = *(const v8s*)(ph + (size_t)arow * 64 + ks * 32 + qd * 8);
          al[ks] = *(const v8s*)(pl + (size_t)arow * 64 + ks * 32 + qd * 8);
        }
      } else {
        v8s z;
#pragma unroll
        for (int j = 0; j < 8; ++j) z[j] = 0;
        ah[0] = ah[1] = al[0] = al[1] = z;
      }
    }
  };

  loadW(0);
  writeW(0, 0);
  __syncthreads();

  for (int s = 0; s < A.nsrc; ++s) {
    loadA(s);                               // 4x16B global (plane path)
    if (s + 1 < A.nsrc) loadW(s + 1);       // prefetch W into regs
    const unsigned short* wh = &sW[s & 1][0][0];
    const unsigned short* wl = &sW[s & 1][1][0];
#pragma unroll
    for (int ks = 0; ks < 2; ++ks) {
#pragma unroll
      for (int ct = 0; ct < 4; ++ct) {
        int wn = ct * 16 + ln;
        v8s bh = *(const v8s*)(wh + wn * 72 + ks * 32 + qd * 8);
        v8s bl = *(const v8s*)(wl + wn * 72 + ks * 32 + qd * 8);
        acc[ct] = __builtin_amdgcn_mfma_f32_16x16x32_bf16(ah[ks], bh, acc[ct], 0, 0, 0);
        acc[ct] = __builtin_amdgcn_mfma_f32_16x16x32_bf16(al[ks], bh, acc[ct], 0, 0, 0);
        acc[ct] = __builtin_amdgcn_mfma_f32_16x16x32_bf16(ah[ks], bl, acc[ct], 0, 0, 0);
      }
    }
    if (s + 1 < A.nsrc) writeW(s + 1, (s + 1) & 1);  // other buffer: no read hazard
    __syncthreads();
  }

  // ---- epilogue: bias + act, write planes, fused colsum ----
  float bvals[4];
#pragma unroll
  for (int ct = 0; ct < 4; ++ct) bvals[ct] = A.bias[ct * 16 + ln];

  float cs[4] = {0.f, 0.f, 0.f, 0.f};
#pragma unroll
  for (int ct = 0; ct < 4; ++ct) {
#pragma unroll
    for (int r = 0; r < 4; ++r) {
      int node = n0 + wv * 16 + qd * 4 + r;   // C/D: row=(lane>>4)*4+reg, col=lane&15
      float v = acc[ct][r] + bvals[ct];
      if (A.relu) v = fmaxf(v, 0.f);
      if (node < A.n) {
        unsigned short h = f2bf(v);
        A.outh[(size_t)node * 64 + ct * 16 + ln] = h;
        A.outl[(size_t)node * 64 + ct * 16 + ln] = f2bf(v - bf2f(h));
        cs[ct] += v;
      }
    }
  }
  if (A.colsum) {
    float* red = (float*)&sW[0][0][0];
#pragma unroll
    for (int ct = 0; ct < 4; ++ct) {
      float v = cs[ct];
      v += __shfl_xor(v, 16, 64);
      v += __shfl_xor(v, 32, 64);
      if (qd == 0) red[wv * 64 + ct * 16 + ln] = v;
    }
    __syncthreads();
    if (t < 64) {
      float ssum = red[t] + red[64 + t] + red[128 + t] + red[192 + t];
      atomicAdd(&A.colsum[t], ssum);
    }
  }
}

// ---------------- tiny post-MLP (single block) ----------------
__global__ __launch_bounds__(256) void k_post(const float* __restrict__ s,
                                              const float* __restrict__ w1, const float* __restrict__ b1,
                                              const float* __restrict__ w2, const float* __restrict__ b2,
                                              const float* __restrict__ w3, const float* __restrict__ b3,
                                              const float* __restrict__ w4, const float* __restrict__ b4,
                                              float* __restrict__ outp) {
  __shared__ float sh[256], h1[64], h2[64], h3[256];
  int t = threadIdx.x;
  sh[t] = s[t];
  __syncthreads();
  if (t < 64) {
    float a = b1[t];
    for (int k = 0; k < 256; ++k) a += sh[k] * w1[k * 64 + t];
    h1[t] = (a >= 0.f) ? a : 0.1f * a;   // leaky_relu 0.1
  }
  __syncthreads();
  if (t < 64) {
    float a = b2[t];
    for (int k = 0; k < 64; ++k) a += h1[k] * w2[k * 64 + t];
    h2[t] = fmaxf(a, 0.f);
  }
  __syncthreads();
  {
    float a = b3[t];
    for (int k = 0; k < 64; ++k) a += h2[k] * w3[k * 256 + t];
    h3[t] = fmaxf(a, 0.f);
  }
  __syncthreads();
  if (t < 64) {
    float a = b4[t];
    for (int k = 0; k < 256; ++k) a += h3[k] * w4[k * 64 + t];
    outp[t] = a;
  }
}

extern "C" void kernel_launch(void* const* d_in, const int* in_sizes, int n_in,
                              void* d_out, int out_size, void* d_ws, size_t ws_size,
                              hipStream_t stream) {
  const float* nf     = (const float*)d_in[0];
  const int*   ei     = (const int*)d_in[1];
  const float* pre_w1 = (const float*)d_in[2];
  const float* pre_b1 = (const float*)d_in[3];
  const float* pre_w2 = (const float*)d_in[4];
  const float* pre_b2 = (const float*)d_in[5];
  const float* skip   = (const float*)d_in[6];
  const float* wl0 = (const float*)d_in[7],  *bl0 = (const float*)d_in[8],  *wr0 = (const float*)d_in[9];
  const float* wl1 = (const float*)d_in[10], *bl1 = (const float*)d_in[11], *wr1 = (const float*)d_in[12];
  const float* wl2 = (const float*)d_in[13], *bl2 = (const float*)d_in[14], *wr2 = (const float*)d_in[15];
  const float* pw1 = (const float*)d_in[16], *pb1 = (const float*)d_in[17];
  const float* pw2 = (const float*)d_in[18], *pb2 = (const float*)d_in[19];
  const float* pw3 = (const float*)d_in[20], *pb3 = (const float*)d_in[21];
  const float* pw4 = (const float*)d_in[22], *pb4 = (const float*)d_in[23];
  float* out = (float*)d_out;

  const int N = NN, E = NE;
  const int NBLK = (N + 255) / 256;   // 196
  const size_t PO = (size_t)N * 64;   // ushorts per plane; lo = hi + PO

  // workspace carve-up
  char* ws = (char*)d_ws;
  size_t pos = 0;
  auto alloc = [&](size_t bytes) {
    char* p = ws + pos;
    pos += (bytes + 255) & ~(size_t)255;
    return (void*)p;
  };
  int*   cnt    = (int*)alloc((size_t)N * 4);
  int*   offs   = (int*)alloc((size_t)(N + 1) * 4);
  int*   cursor = (int*)alloc((size_t)N * 4);
  int*   csr    = (int*)alloc((size_t)E * 4);
  float* invd   = (float*)alloc((size_t)N * 4);
  int*   bsum   = (int*)alloc((size_t)NBLK * 4);
  const size_t PB = PO * 2 * 2;       // hi+lo planes, bytes (12.8 MB)
  unsigned short* x  = (unsigned short*)alloc(PB);
  unsigned short* h0 = (unsigned short*)alloc(PB);
  unsigned short* h1 = (unsigned short*)alloc(PB);
  unsigned short* h2 = (unsigned short*)alloc(PB);
  unsigned short* m0 = (unsigned short*)alloc(PB);
  unsigned short* m1 = (unsigned short*)alloc(PB);
  unsigned short* m2 = (unsigned short*)alloc(PB);
  unsigned short* t0 = m2;            // pre-MLP hidden; dead before m2 is written
  float* sv = (float*)alloc(256 * 4);

  hipMemsetAsync(cnt, 0, (size_t)N * 4, stream);
  hipMemsetAsync(sv, 0, 256 * 4, stream);

  const int* e_src = ei;
  const int* e_dst = ei + E;
  k_deg<<<(E + 255) / 256, 256, 0, stream>>>(e_dst, E, cnt);
  k_blockred<<<NBLK, 256, 0, stream>>>(cnt, N, bsum);
  k_scanb<<<1, 256, 0, stream>>>(bsum, NBLK, offs + N);
  k_scanfinal<<<NBLK, 256, 0, stream>>>(cnt, N, bsum, offs, cursor, invd);
  k_scatter<<<(E + 255) / 256, 256, 0, stream>>>(e_src, e_dst, E, cursor, csr);

  const int LGRID = (N + 63) / 64;   // 782
  auto lin = [&](int nsrc,
                 const void* a0, int f0, int s0, const float* w0, int g0,
                 const void* a1, int f1, int s1, const float* w1_, int g1,
                 const void* a2, int f2, int s2, const float* w2_, int g2,
                 const void* a3, int f3, int s3, const float* w3_, int g3,
                 const void* a4, int f4, int s4, const float* w4_, int g4,
                 const void* a5, int f5, int s5, const float* w5_, int g5,
                 const float* bias, unsigned short* oh, float* colsum, int relu) {
    LinArgs A;
    A.a[0] = a0; A.a[1] = a1; A.a[2] = a2; A.a[3] = a3; A.a[4] = a4; A.a[5] = a5;
    A.w[0] = w0; A.w[1] = w1_; A.w[2] = w2_; A.w[3] = w3_; A.w[4] = w4_; A.w[5] = w5_;
    A.gidx[0] = g0; A.gidx[1] = g1; A.gidx[2] = g2; A.gidx[3] = g3; A.gidx[4] = g4; A.gidx[5] = g5;
    A.stride[0] = s0; A.stride[1] = s1; A.stride[2] = s2; A.stride[3] = s3; A.stride[4] = s4; A.stride[5] = s5;
    A.isf32[0] = f0; A.isf32[1] = f1; A.isf32[2] = f2; A.isf32[3] = f3; A.isf32[4] = f4; A.isf32[5] = f5;
    A.plane_off = PO;
    A.nsrc = nsrc; A.bias = bias; A.skip = skip;
    A.outh = oh; A.outl = oh + PO; A.colsum = colsum;
    A.n = N; A.relu = relu;
    k_linear<<<LGRID, 256, 0, stream>>>(A);
  };

  // pre_mlp pass1: t0 = relu(nf @ pre_w1 + pre_b1)  (K=128 -> 2 fp32 sources)
  lin(2, nf, 1, 128, pre_w1, -1, nf + 64, 1, 128, pre_w1 + 64 * 64, -1,
      nullptr, 0, 0, nullptr, -1, nullptr, 0, 0, nullptr, -1,
      nullptr, 0, 0, nullptr, -1, nullptr, 0, 0, nullptr, -1,
      pre_b1, t0, nullptr, 1);
  // pre_mlp pass2: x = t0 @ pre_w2 + pre_b2  (fused colsum -> sv[0:64])
  lin(1, t0, 0, 0, pre_w2, -1,
      nullptr, 0, 0, nullptr, -1, nullptr, 0, 0, nullptr, -1,
      nullptr, 0, 0, nullptr, -1, nullptr, 0, 0, nullptr, -1,
      nullptr, 0, 0, nullptr, -1, pre_b2, x, sv, 0);

  // layer 0
  k_aggregate<<<(N + 3) / 4, 256, 0, stream>>>(x, x + PO, offs, csr, invd, m0, m0 + PO, N);
  lin(2, m0, 0, 0, wl0, 0, x, 0, 0, wr0, 0,
      nullptr, 0, 0, nullptr, -1, nullptr, 0, 0, nullptr, -1,
      nullptr, 0, 0, nullptr, -1, nullptr, 0, 0, nullptr, -1,
      bl0, h0, sv + 64, 1);

  // layer 1 (gates skip[1][0]=idx3, skip[1][1]=idx4)
  k_aggregate<<<(N + 3) / 4, 256, 0, stream>>>(h0, h0 + PO, offs, csr, invd, m1, m1 + PO, N);
  lin(4, m0, 0, 0, wl1, 3, m1, 0, 0, wl1 + 64 * 64, 4,
      x, 0, 0, wr1, 3, h0, 0, 0, wr1 + 64 * 64, 4,
      nullptr, 0, 0, nullptr, -1, nullptr, 0, 0, nullptr, -1,
      bl1, h1, sv + 128, 1);

  // layer 2 (gates skip[2][0..2] = idx 6,7,8)
  k_aggregate<<<(N + 3) / 4, 256, 0, stream>>>(h1, h1 + PO, offs, csr, invd, m2, m2 + PO, N);
  lin(6, m0, 0, 0, wl2, 6, m1, 0, 0, wl2 + 64 * 64, 7, m2, 0, 0, wl2 + 128 * 64, 8,
      x, 0, 0, wr2, 6, h0, 0, 0, wr2 + 64 * 64, 7, h1, 0, 0, wr2 + 128 * 64, 8,
      bl2, h2, sv + 192, 1);

  // post-MLP on the fused column sums
  k_post<<<1, 256, 0, stream>>>(sv, pw1, pb1, pw2, pb2, pw3, pb3, pw4, pb4, out);
}

// Round 8
// 394.899 us; speedup vs baseline: 1.4832x; 1.1419x over previous
//
#include <hip/hip_runtime.h>
#include <math.h>

#define NN 50000
#define NE 800000
#define NB 196        // dst buckets of 256 nodes: (NN+255)>>8

typedef float v4f __attribute__((ext_vector_type(4)));
typedef short v8s __attribute__((ext_vector_type(8)));

__device__ __forceinline__ unsigned short f2bf(float f) {
  unsigned u = __float_as_uint(f);
  u = u + 0x7FFFu + ((u >> 16) & 1u);
  return (unsigned short)(u >> 16);
}
__device__ __forceinline__ float bf2f(unsigned short h) {
  return __uint_as_float(((unsigned)h) << 16);
}

// ================= graph build: two-level bucket sort (dense writes) ==========

// Phase A: bucket histogram (bucket = dst>>8)
__global__ __launch_bounds__(256) void k_bhist(const int* __restrict__ dst,
                                               int* __restrict__ gbcnt) {
  __shared__ int lcnt[NB];
  int t = threadIdx.x;
  for (int i = t; i < NB; i += 256) lcnt[i] = 0;
  __syncthreads();
  int eb = blockIdx.x * 4096;
#pragma unroll
  for (int i = 0; i < 16; ++i) {
    int e = eb + i * 256 + t;
    if (e < NE) atomicAdd(&lcnt[dst[e] >> 8], 1);
  }
  __syncthreads();
  for (int i = t; i < NB; i += 256)
    if (lcnt[i]) atomicAdd(&gbcnt[i], lcnt[i]);
}

// Phase B: scan bucket counts -> boff[NB+1]; init cursors; offs[NN]=NE
__global__ __launch_bounds__(256) void k_bscan(const int* __restrict__ gbcnt,
                                               int* __restrict__ boff,
                                               int* __restrict__ gcur,
                                               int* __restrict__ offs) {
  __shared__ int sd[256];
  int t = threadIdx.x;
  int v = (t < NB) ? gbcnt[t] : 0;
  sd[t] = v;
  __syncthreads();
  for (int o = 1; o < 256; o <<= 1) {
    int u = (t >= o) ? sd[t - o] : 0;
    __syncthreads();
    sd[t] += u;
    __syncthreads();
  }
  if (t < NB) { int x = sd[t] - v; boff[t] = x; gcur[t] = x; }
  if (t == NB - 1) boff[NB] = sd[t];
  if (t == 0) offs[NN] = NE;
}

// Phase C: scatter packed edges into bucketed ebuf (per-block range reservation)
__global__ __launch_bounds__(256) void k_bscatter(const int* __restrict__ src,
                                                  const int* __restrict__ dst,
                                                  int* __restrict__ gcur,
                                                  unsigned* __restrict__ ebuf) {
  __shared__ int cnt[NB];
  __shared__ int base[NB];
  int t = threadIdx.x;
  for (int i = t; i < NB; i += 256) cnt[i] = 0;
  __syncthreads();
  int eb = blockIdx.x * 4096;
  unsigned pk[16];
  int bk[16], lp[16];
#pragma unroll
  for (int i = 0; i < 16; ++i) {
    int e = eb + i * 256 + t;
    if (e < NE) {
      int d = dst[e];
      int b = d >> 8;
      pk[i] = ((unsigned)src[e] << 8) | (unsigned)(d & 255);
      bk[i] = b;
      lp[i] = atomicAdd(&cnt[b], 1);
    }
  }
  __syncthreads();
  for (int i = t; i < NB; i += 256)
    base[i] = cnt[i] ? atomicAdd(&gcur[i], cnt[i]) : 0;
  __syncthreads();
#pragma unroll
  for (int i = 0; i < 16; ++i) {
    int e = eb + i * 256 + t;
    if (e < NE) ebuf[base[bk[i]] + lp[i]] = pk[i];
  }
}

// Phase D: per-bucket: degree count + scan in LDS -> offs/invd; scatter src into
// a contiguous 16KB csr window (dense full-line writebacks).
__global__ __launch_bounds__(256) void k_bbuild(const unsigned* __restrict__ ebuf,
                                                const int* __restrict__ boff,
                                                int* __restrict__ offs,
                                                float* __restrict__ invd,
                                                int* __restrict__ csr) {
  __shared__ int dcnt[256];
  __shared__ int cur[256];
  int t = threadIdx.x;
  int b = blockIdx.x;
  int node0 = b << 8;
  int es = boff[b], ee = boff[b + 1];
  dcnt[t] = 0;
  __syncthreads();
  for (int e = es + t; e < ee; e += 256) atomicAdd(&dcnt[ebuf[e] & 255], 1);
  __syncthreads();
  int v = dcnt[t];
  cur[t] = v;
  __syncthreads();
  for (int o = 1; o < 256; o <<= 1) {
    int u = (t >= o) ? cur[t - o] : 0;
    __syncthreads();
    cur[t] += u;
    __syncthreads();
  }
  int excl = cur[t] - v;
  int node = node0 + t;
  if (node < NN) {
    offs[node] = es + excl;
    invd[node] = 1.0f / fmaxf((float)v, 1.0f);
  }
  __syncthreads();
  cur[t] = es + excl;
  __syncthreads();
  for (int e = es + t; e < ee; e += 256) {
    unsigned pk = ebuf[e];
    int p = atomicAdd(&cur[pk & 255], 1);
    csr[p] = (int)(pk >> 8);
  }
}

// ================= per-node mean aggregation (interleaved hi|lo rows) =========
// feat: [n][128] ushort (cols 0-63 hi, 64-127 lo) -> one 256B burst per row.
// lane = nsub*16 + cg; 16 rows in flight (4 slots x 4-deep unroll).
// reduce: xor8 folds hi+lo (plane bit), xor16/32 fold neighbor slots.
__global__ __launch_bounds__(256) void k_aggregate(
    const unsigned short* __restrict__ feat,
    const int* __restrict__ offs, const int* __restrict__ csr,
    const float* __restrict__ invd,
    unsigned short* __restrict__ mean, int n) {
  int node = blockIdx.x * 4 + (threadIdx.x >> 6);
  int lane = threadIdx.x & 63;
  int nsub = lane >> 4;     // 0..3 neighbor slot
  int cg   = lane & 15;     // 16 groups x 8 ushort = full 256B row
  if (node >= n) return;
  int s = offs[node], e = offs[node + 1];

  float a[8];
#pragma unroll
  for (int i = 0; i < 8; ++i) a[i] = 0.f;

  if (e > s) {
    int emax = e - 1;
    for (int p0 = s; p0 < e; p0 += 16) {
      int pa = p0 + nsub, pb = p0 + 4 + nsub, pc = p0 + 8 + nsub, pd = p0 + 12 + nsub;
      int ja = csr[pa < emax ? pa : emax];
      int jb = csr[pb < emax ? pb : emax];
      int jc = csr[pc < emax ? pc : emax];
      int jd = csr[pd < emax ? pd : emax];
      v8s va = *(const v8s*)(feat + (size_t)ja * 128 + cg * 8);
      v8s vb = *(const v8s*)(feat + (size_t)jb * 128 + cg * 8);
      v8s vc = *(const v8s*)(feat + (size_t)jc * 128 + cg * 8);
      v8s vd = *(const v8s*)(feat + (size_t)jd * 128 + cg * 8);
      if (pa < e) {
#pragma unroll
        for (int i = 0; i < 8; ++i) a[i] += bf2f((unsigned short)va[i]);
      }
      if (pb < e) {
#pragma unroll
        for (int i = 0; i < 8; ++i) a[i] += bf2f((unsigned short)vb[i]);
      }
      if (pc < e) {
#pragma unroll
        for (int i = 0; i < 8; ++i) a[i] += bf2f((unsigned short)vc[i]);
      }
      if (pd < e) {
#pragma unroll
        for (int i = 0; i < 8; ++i) a[i] += bf2f((unsigned short)vd[i]);
      }
    }
  }
#pragma unroll
  for (int i = 0; i < 8; ++i) {
    a[i] += __shfl_xor(a[i], 8, 64);   // hi + lo plane
    a[i] += __shfl_xor(a[i], 16, 64);  // neighbor slots
    a[i] += __shfl_xor(a[i], 32, 64);
  }
  if (lane < 8) {
    float d = invd[node];
    v8s oh, ol;
#pragma unroll
    for (int i = 0; i < 8; ++i) {
      float m = a[i] * d;
      unsigned short h = f2bf(m);
      oh[i] = (short)h;
      ol[i] = (short)f2bf(m - bf2f(h));
    }
    *(v8s*)(mean + (size_t)node * 128 + lane * 8) = oh;
    *(v8s*)(mean + (size_t)node * 128 + 64 + lane * 8) = ol;
  }
}

// ================= fused multi-source linear, MFMA split-bf16 =================
// out = act( sum_s A_s @ (g_s W_s) + bias ); A,W split hi/lo -> 3 MFMAs/product.
// Feature rows interleaved [n][128] (hi|lo). W^T staged in LDS (144B stride).
struct LinArgs {
  const void*  a[6];       // fp32 ptr (isf32) or bf16 interleaved-row ptr
  const float* w[6];       // [64][64] fp32 blocks (row stride 64)
  int gidx[6];
  int stride[6];           // fp32 row stride
  int isf32[6];
  int nsrc;
  const float* bias;
  const float* skip;
  unsigned short* outp;    // [n][128] interleaved hi|lo
  float* colsum;           // [64] atomic target, or nullptr
  int n;
  int relu;
};

__global__ __launch_bounds__(256) void k_linear(LinArgs A) {
  __shared__ unsigned short sW[2][2][64 * 72];   // [buf][hi/lo][n*72+k]
  const int t    = threadIdx.x;
  const int lane = t & 63;
  const int wv   = t >> 6;
  const int qd   = lane >> 4;
  const int ln   = lane & 15;
  const int n0   = blockIdx.x * 64;

  v4f acc[4];
#pragma unroll
  for (int ct = 0; ct < 4; ++ct) acc[ct] = (v4f){0.f, 0.f, 0.f, 0.f};

  const int sn = t & 63;
  float wreg[16];
  auto loadW = [&](int s) {
    const float* w = A.w[s];
#pragma unroll
    for (int c = 0; c < 2; ++c) {
      int kb = (wv + 4 * c) * 8;
#pragma unroll
      for (int j = 0; j < 8; ++j)
        wreg[c * 8 + j] = w[(size_t)(kb + j) * 64 + sn];
    }
  };
  auto writeW = [&](int s, int b) {
    float gs = 1.0f;
    if (A.gidx[s] >= 0) gs = 1.0f / (1.0f + __expf(-A.skip[A.gidx[s]]));
#pragma unroll
    for (int c = 0; c < 2; ++c) {
      int cb = wv + 4 * c;
      v8s hv, lv;
#pragma unroll
      for (int j = 0; j < 8; ++j) {
        float f = wreg[c * 8 + j] * gs;
        unsigned short h = f2bf(f);
        hv[j] = (short)h;
        lv[j] = (short)f2bf(f - bf2f(h));
      }
      *(v8s*)(&sW[b][0][sn * 72 + cb * 8]) = hv;
      *(v8s*)(&sW[b][1][sn * 72 + cb * 8]) = lv;
    }
  };

  const int arow = n0 + wv * 16 + ln;
  const bool arv = arow < A.n;
  v8s ah[2], al[2];
  auto loadA = [&](int s) {
    if (A.isf32[s]) {
      const float* a = (const float*)A.a[s];
      int st = A.stride[s];
#pragma unroll
      for (int ks = 0; ks < 2; ++ks) {
        float f[8];
        if (arv) {
          const float* p = a + (size_t)arow * st + ks * 32 + qd * 8;
          float4 u0 = *(const float4*)(p);
          float4 u1 = *(const float4*)(p + 4);
          f[0] = u0.x; f[1] = u0.y; f[2] = u0.z; f[3] = u0.w;
          f[4] = u1.x; f[5] = u1.y; f[6] = u1.z; f[7] = u1.w;
        } else {
#pragma unroll
          for (int j = 0; j < 8; ++j) f[j] = 0.f;
        }
        v8s hv, lv;
#pragma unroll
        for (int j = 0; j < 8; ++j) {
          unsigned short h = f2bf(f[j]);
          hv[j] = (short)h;
          lv[j] = (short)f2bf(f[j] - bf2f(h));
        }
        ah[ks] = hv; al[ks] = lv;
      }
    } else {
      const unsigned short* ph = (const unsigned short*)A.a[s] + (size_t)arow * 128;
      if (arv) {
#pragma unroll
        for (int ks = 0; ks < 2; ++ks) {
          ah[ks] = *(const v8s*)(ph + ks * 32 + qd * 8);
          al[ks] = *(const v8s*)(ph + 64 + ks * 32 + qd * 8);
        }
      } else {
        v8s z;
#pragma unroll
        for (int j = 0; j < 8; ++j) z[j] = 0;
        ah[0] = ah[1] = al[0] = al[1] = z;
      }
    }
  };

  loadW(0);
  writeW(0, 0);
  __syncthreads();

  for (int s = 0; s < A.nsrc; ++s) {
    loadA(s);
    if (s + 1 < A.nsrc) loadW(s + 1);
    const unsigned short* wh = &sW[s & 1][0][0];
    const unsigned short* wl = &sW[s & 1][1][0];
#pragma unroll
    for (int ks = 0; ks < 2; ++ks) {
#pragma unroll
      for (int ct = 0; ct < 4; ++ct) {
        int wn = ct * 16 + ln;
        v8s bh = *(const v8s*)(wh + wn * 72 + ks * 32 + qd * 8);
        v8s bl = *(const v8s*)(wl + wn * 72 + ks * 32 + qd * 8);
        acc[ct] = __builtin_amdgcn_mfma_f32_16x16x32_bf16(ah[ks], bh, acc[ct], 0, 0, 0);
        acc[ct] = __builtin_amdgcn_mfma_f32_16x16x32_bf16(al[ks], bh, acc[ct], 0, 0, 0);
        acc[ct] = __builtin_amdgcn_mfma_f32_16x16x32_bf16(ah[ks], bl, acc[ct], 0, 0, 0);
      }
    }
    if (s + 1 < A.nsrc) writeW(s + 1, (s + 1) & 1);
    __syncthreads();
  }

  float bvals[4];
#pragma unroll
  for (int ct = 0; ct < 4; ++ct) bvals[ct] = A.bias[ct * 16 + ln];

  float cs[4] = {0.f, 0.f, 0.f, 0.f};
#pragma unroll
  for (int ct = 0; ct < 4; ++ct) {
#pragma unroll
    for (int r = 0; r < 4; ++r) {
      int node = n0 + wv * 16 + qd * 4 + r;   // C/D: row=(lane>>4)*4+reg, col=lane&15
      float v = acc[ct][r] + bvals[ct];
      if (A.relu) v = fmaxf(v, 0.f);
      if (node < A.n) {
        unsigned short h = f2bf(v);
        A.outp[(size_t)node * 128 + ct * 16 + ln] = h;
        A.outp[(size_t)node * 128 + 64 + ct * 16 + ln] = f2bf(v - bf2f(h));
        cs[ct] += v;
      }
    }
  }
  if (A.colsum) {
    float* red = (float*)&sW[0][0][0];
#pragma unroll
    for (int ct = 0; ct < 4; ++ct) {
      float v = cs[ct];
      v += __shfl_xor(v, 16, 64);
      v += __shfl_xor(v, 32, 64);
      if (qd == 0) red[wv * 64 + ct * 16 + ln] = v;
    }
    __syncthreads();
    if (t < 64) {
      float ssum = red[t] + red[64 + t] + red[128 + t] + red[192 + t];
      atomicAdd(&A.colsum[t], ssum);
    }
  }
}

// ---------------- tiny post-MLP (single block) ----------------
__global__ __launch_bounds__(256) void k_post(const float* __restrict__ s,
                                              const float* __restrict__ w1, const float* __restrict__ b1,
                                              const float* __restrict__ w2, const float* __restrict__ b2,
                                              const float* __restrict__ w3, const float* __restrict__ b3,
                                              const float* __restrict__ w4, const float* __restrict__ b4,
                                              float* __restrict__ outp) {
  __shared__ float sh[256], h1[64], h2[64], h3[256];
  int t = threadIdx.x;
  sh[t] = s[t];
  __syncthreads();
  if (t < 64) {
    float a = b1[t];
    for (int k = 0; k < 256; ++k) a += sh[k] * w1[k * 64 + t];
    h1[t] = (a >= 0.f) ? a : 0.1f * a;   // leaky_relu 0.1
  }
  __syncthreads();
  if (t < 64) {
    float a = b2[t];
    for (int k = 0; k < 64; ++k) a += h1[k] * w2[k * 64 + t];
    h2[t] = fmaxf(a, 0.f);
  }
  __syncthreads();
  {
    float a = b3[t];
    for (int k = 0; k < 64; ++k) a += h2[k] * w3[k * 256 + t];
    h3[t] = fmaxf(a, 0.f);
  }
  __syncthreads();
  if (t < 64) {
    float a = b4[t];
    for (int k = 0; k < 256; ++k) a += h3[k] * w4[k * 64 + t];
    outp[t] = a;
  }
}

extern "C" void kernel_launch(void* const* d_in, const int* in_sizes, int n_in,
                              void* d_out, int out_size, void* d_ws, size_t ws_size,
                              hipStream_t stream) {
  const float* nf     = (const float*)d_in[0];
  const int*   ei     = (const int*)d_in[1];
  const float* pre_w1 = (const float*)d_in[2];
  const float* pre_b1 = (const float*)d_in[3];
  const float* pre_w2 = (const float*)d_in[4];
  const float* pre_b2 = (const float*)d_in[5];
  const float* skip   = (const float*)d_in[6];
  const float* wl0 = (const float*)d_in[7],  *bl0 = (const float*)d_in[8],  *wr0 = (const float*)d_in[9];
  const float* wl1 = (const float*)d_in[10], *bl1 = (const float*)d_in[11], *wr1 = (const float*)d_in[12];
  const float* wl2 = (const float*)d_in[13], *bl2 = (const float*)d_in[14], *wr2 = (const float*)d_in[15];
  const float* pw1 = (const float*)d_in[16], *pb1 = (const float*)d_in[17];
  const float* pw2 = (const float*)d_in[18], *pb2 = (const float*)d_in[19];
  const float* pw3 = (const float*)d_in[20], *pb3 = (const float*)d_in[21];
  const float* pw4 = (const float*)d_in[22], *pb4 = (const float*)d_in[23];
  float* out = (float*)d_out;

  const int N = NN, E = NE;

  // workspace carve-up
  char* ws = (char*)d_ws;
  size_t pos = 0;
  auto alloc = [&](size_t bytes) {
    char* p = ws + pos;
    pos += (bytes + 255) & ~(size_t)255;
    return (void*)p;
  };
  int*      gbcnt = (int*)alloc((size_t)NB * 4);
  int*      boff  = (int*)alloc((size_t)(NB + 1) * 4);
  int*      gcur  = (int*)alloc((size_t)NB * 4);
  unsigned* ebuf  = (unsigned*)alloc((size_t)E * 4);
  int*      offs  = (int*)alloc((size_t)(N + 1) * 4);
  float*    invd  = (float*)alloc((size_t)N * 4);
  int*      csr   = (int*)alloc((size_t)E * 4);
  const size_t PB = (size_t)N * 128 * 2;   // interleaved hi|lo rows, bytes
  unsigned short* x  = (unsigned short*)alloc(PB);
  unsigned short* h0 = (unsigned short*)alloc(PB);
  unsigned short* h1 = (unsigned short*)alloc(PB);
  unsigned short* h2 = (unsigned short*)alloc(PB);
  unsigned short* m0 = (unsigned short*)alloc(PB);
  unsigned short* m1 = (unsigned short*)alloc(PB);
  unsigned short* m2 = (unsigned short*)alloc(PB);
  unsigned short* t0 = m2;            // pre-MLP hidden; dead before m2 is written
  float* sv = (float*)alloc(256 * 4);

  hipMemsetAsync(gbcnt, 0, (size_t)NB * 4, stream);
  hipMemsetAsync(sv, 0, 256 * 4, stream);

  const int* e_src = ei;
  const int* e_dst = ei + E;
  const int EGRID = (E + 4095) / 4096;   // 196
  k_bhist<<<EGRID, 256, 0, stream>>>(e_dst, gbcnt);
  k_bscan<<<1, 256, 0, stream>>>(gbcnt, boff, gcur, offs);
  k_bscatter<<<EGRID, 256, 0, stream>>>(e_src, e_dst, gcur, ebuf);
  k_bbuild<<<NB, 256, 0, stream>>>(ebuf, boff, offs, invd, csr);

  const int LGRID = (N + 63) / 64;   // 782
  auto lin = [&](int nsrc,
                 const void* a0, int f0, int s0, const float* w0, int g0,
                 const void* a1, int f1, int s1, const float* w1_, int g1,
                 const void* a2, int f2, int s2, const float* w2_, int g2,
                 const void* a3, int f3, int s3, const float* w3_, int g3,
                 const void* a4, int f4, int s4, const float* w4_, int g4,
                 const void* a5, int f5, int s5, const float* w5_, int g5,
                 const float* bias, unsigned short* op, float* colsum, int relu) {
    LinArgs A;
    A.a[0] = a0; A.a[1] = a1; A.a[2] = a2; A.a[3] = a3; A.a[4] = a4; A.a[5] = a5;
    A.w[0] = w0; A.w[1] = w1_; A.w[2] = w2_; A.w[3] = w3_; A.w[4] = w4_; A.w[5] = w5_;
    A.gidx[0] = g0; A.gidx[1] = g1; A.gidx[2] = g2; A.gidx[3] = g3; A.gidx[4] = g4; A.gidx[5] = g5;
    A.stride[0] = s0; A.stride[1] = s1; A.stride[2] = s2; A.stride[3] = s3; A.stride[4] = s4; A.stride[5] = s5;
    A.isf32[0] = f0; A.isf32[1] = f1; A.isf32[2] = f2; A.isf32[3] = f3; A.isf32[4] = f4; A.isf32[5] = f5;
    A.nsrc = nsrc; A.bias = bias; A.skip = skip;
    A.outp = op; A.colsum = colsum;
    A.n = N; A.relu = relu;
    k_linear<<<LGRID, 256, 0, stream>>>(A);
  };

  // pre_mlp pass1: t0 = relu(nf @ pre_w1 + pre_b1)  (K=128 -> 2 fp32 sources)
  lin(2, nf, 1, 128, pre_w1, -1, nf + 64, 1, 128, pre_w1 + 64 * 64, -1,
      nullptr, 0, 0, nullptr, -1, nullptr, 0, 0, nullptr, -1,
      nullptr, 0, 0, nullptr, -1, nullptr, 0, 0, nullptr, -1,
      pre_b1, t0, nullptr, 1);
  // pre_mlp pass2: x = t0 @ pre_w2 + pre_b2  (fused colsum -> sv[0:64])
  lin(1, t0, 0, 0, pre_w2, -1,
      nullptr, 0, 0, nullptr, -1, nullptr, 0, 0, nullptr, -1,
      nullptr, 0, 0, nullptr, -1, nullptr, 0, 0, nullptr, -1,
      nullptr, 0, 0, nullptr, -1, pre_b2, x, sv, 0);

  // layer 0
  k_aggregate<<<(N + 3) / 4, 256, 0, stream>>>(x, offs, csr, invd, m0, N);
  lin(2, m0, 0, 0, wl0, 0, x, 0, 0, wr0, 0,
      nullptr, 0, 0, nullptr, -1, nullptr, 0, 0, nullptr, -1,
      nullptr, 0, 0, nullptr, -1, nullptr, 0, 0, nullptr, -1,
      bl0, h0, sv + 64, 1);

  // layer 1 (gates skip[1][0]=idx3, skip[1][1]=idx4)
  k_aggregate<<<(N + 3) / 4, 256, 0, stream>>>(h0, offs, csr, invd, m1, N);
  lin(4, m0, 0, 0, wl1, 3, m1, 0, 0, wl1 + 64 * 64, 4,
      x, 0, 0, wr1, 3, h0, 0, 0, wr1 + 64 * 64, 4,
      nullptr, 0, 0, nullptr, -1, nullptr, 0, 0, nullptr, -1,
      bl1, h1, sv + 128, 1);

  // layer 2 (gates skip[2][0..2] = idx 6,7,8)
  k_aggregate<<<(N + 3) / 4, 256, 0, stream>>>(h1, offs, csr, invd, m2, N);
  lin(6, m0, 0, 0, wl2, 6, m1, 0, 0, wl2 + 64 * 64, 7, m2, 0, 0, wl2 + 128 * 64, 8,
      x, 0, 0, wr2, 6, h0, 0, 0, wr2 + 64 * 64, 7, h1, 0, 0, wr2 + 128 * 64, 8,
      bl2, h2, sv + 192, 1);

  // post-MLP on the fused column sums
  k_post<<<1, 256, 0, stream>>>(sv, pw1, pb1, pw2, pb2, pw3, pb3, pw4, pb4, out);
}